// Round 12
// baseline (285.606 us; speedup 1.0000x reference)
//
#include <hip/hip_runtime.h>
#include <math.h>

#define NN 131072
#define BBG 1024
#define MMN 128
#define DDF 256
#define KKC 32

// ---- d_out offsets (floats), concatenated in reference return order ----
#define OFF_S      0
#define OFF_HFLAT  4194304
#define OFF_HDENSE 12582912
#define OFF_P      20971520
#define OFF_PHAT   22020096
#define OFF_ZD     23068672
#define OFF_G      56623104
#define OFF_MASK   56885248
#define OFF_UNEW   56918016

// ---- ws offsets (floats) ----
#define WS_PSUM  0          // [1024][256]
#define WS_PSQ   524288     // [1024][256]
#define WS_TMP   1048576    // [16][256]
#define WS_SCALE 1052672    // [256]
#define WS_SHIFT 1052928    // [256]
#define WS_UN    1053184    // [32][256]
#define WS_SF    1061376    // [N][32]
#define WS_C     5255680    // [B][32]
#define WS_PART  5288448    // [8*32][256]

typedef __attribute__((ext_vector_type(8))) short short8;
typedef __attribute__((ext_vector_type(4))) float f32x4;

// raw barrier with lgkm-only drain: global loads/stores stay in flight (T4)
#define LGKM_BAR() do { asm volatile("s_waitcnt lgkmcnt(0)" ::: "memory"); \
  __builtin_amdgcn_s_barrier(); __builtin_amdgcn_sched_barrier(0); } while (0)

__device__ __forceinline__ unsigned short f2bf(float x) {
  unsigned u = __float_as_uint(x);
  u += 0x7fffu + ((u >> 16) & 1u);
  return (unsigned short)(u >> 16);
}
__device__ __forceinline__ float bf2f(unsigned short h) {
  return __uint_as_float(((unsigned)h) << 16);
}

// ============ K0: W1 -> blocked bf16 hi/lo  +  Un = U/||U|| ============
__global__ __launch_bounds__(256) void k0_prep(const float* __restrict__ W1,
    const float* __restrict__ U, unsigned short* __restrict__ preh,
    unsigned short* __restrict__ prel, float* __restrict__ Un)
{
  if (blockIdx.x < 32) {
    int tid = blockIdx.x * 256 + threadIdx.x;   // < 8192
    int n = tid & 255, kq = tid >> 8;           // kq in [0,32): k = kq*8 + j
    short8 hv, lv;
    #pragma unroll
    for (int j = 0; j < 8; ++j) {
      float v = W1[(kq * 8 + j) * DDF + n];
      unsigned short hb = f2bf(v);
      hv[j] = (short)hb;
      lv[j] = (short)f2bf(v - bf2f(hb));
    }
    int base = (kq >> 2) * 8192 + (kq & 3) * 2048 + n * 8;
    *(short8*)(preh + base) = hv;
    *(short8*)(prel + base) = lv;
  } else {
    int k = (blockIdx.x - 32) * 4 + (threadIdx.x >> 6);  // 32 rows
    int l = threadIdx.x & 63;
    float4 u = *(const float4*)(U + k*256 + l*4);
    float ss = u.x*u.x + u.y*u.y + u.z*u.z + u.w*u.w;
    #pragma unroll
    for (int off = 32; off >= 1; off >>= 1) ss += __shfl_xor(ss, off);
    float inv = 1.0f / fmaxf(sqrtf(ss), 1e-12f);
    *(float4*)(Un + k*256 + l*4) = make_float4(u.x*inv, u.y*inv, u.z*inv, u.w*inv);
  }
}

// ============ K1: h1 = z@W1 + b1, 3-term bf16x2 MFMA, BK=64 ============
// 1024 blocks x 512 thr (8 waves, 2x4 grid, 64x64/wave). 4 K-steps of 64:
// half the LGKM_BARs of BK=32, 96 MFMA per phase. LDS 73.7 KB (occupancy is
// reg-bound at 2 waves/SIMD either way -> BK=64 costs nothing). Row stride
// 72 shorts: read banks (4*l16+4*lg+16*ks2)%32 -> 8/bank = b128 minimum.
__device__ __forceinline__ void cvt_storeA(float4 za, float4 zb,
    unsigned short* AhB, unsigned short* AlB, int arow, int ac)
{
  unsigned short h0 = f2bf(za.x), h1v = f2bf(za.y), h2 = f2bf(za.z), h3 = f2bf(za.w);
  unsigned short g0 = f2bf(zb.x), g1 = f2bf(zb.y), g2 = f2bf(zb.z), g3 = f2bf(zb.w);
  uint2 hA = make_uint2((unsigned)h0 | ((unsigned)h1v << 16),
                        (unsigned)h2 | ((unsigned)h3 << 16));
  uint2 hB = make_uint2((unsigned)g0 | ((unsigned)g1 << 16),
                        (unsigned)g2 | ((unsigned)g3 << 16));
  uint2 lA = make_uint2((unsigned)f2bf(za.x - bf2f(h0)) | ((unsigned)f2bf(za.y - bf2f(h1v)) << 16),
                        (unsigned)f2bf(za.z - bf2f(h2)) | ((unsigned)f2bf(za.w - bf2f(h3)) << 16));
  uint2 lB = make_uint2((unsigned)f2bf(zb.x - bf2f(g0)) | ((unsigned)f2bf(zb.y - bf2f(g1)) << 16),
                        (unsigned)f2bf(zb.z - bf2f(g2)) | ((unsigned)f2bf(zb.w - bf2f(g3)) << 16));
  *(uint2*)(AhB + arow * 72 + ac * 4)      = hA;
  *(uint2*)(AhB + arow * 72 + 16 + ac * 4) = hB;
  *(uint2*)(AlB + arow * 72 + ac * 4)      = lA;
  *(uint2*)(AlB + arow * 72 + 16 + ac * 4) = lB;
}

__global__ __launch_bounds__(512) void k1_gemm1(
    const float* __restrict__ z, const unsigned short* __restrict__ preh,
    const unsigned short* __restrict__ prel, const float* __restrict__ b1,
    float* __restrict__ h1, float* __restrict__ psum, float* __restrict__ psq)
{
  __shared__ __attribute__((aligned(16))) unsigned short Ah[2 * 128 * 72]; // 36 KB
  __shared__ __attribute__((aligned(16))) unsigned short Al[2 * 128 * 72]; // 36 KB

  const int t = threadIdx.x;
  const int l = t & 63;
  const int w = t >> 6;
  const int wr = w >> 2;
  const int wc = w & 3;
  const int lg = l >> 4;
  const int l16 = l & 15;
  const int n0 = blockIdx.x * 128;

  f32x4 acc[4][4];
  #pragma unroll
  for (int i = 0; i < 4; ++i)
    #pragma unroll
    for (int j = 0; j < 4; ++j) acc[i][j] = (f32x4)0.0f;

  const int arow = t >> 2, ac = t & 3;
  const float* zrow = z + (size_t)(n0 + arow) * DDF;
  const unsigned short* bhbase = preh + lg * 2048 + wc * 512 + l16 * 8;
  const unsigned short* blbase = prel + lg * 2048 + wc * 512 + l16 * 8;

  // prologue: stage A-step0 (cols 0..63)
  {
    float4 p0 = *(const float4*)(zrow + ac * 4);
    float4 p1 = *(const float4*)(zrow + 16 + ac * 4);
    float4 p2 = *(const float4*)(zrow + 32 + ac * 4);
    float4 p3 = *(const float4*)(zrow + 48 + ac * 4);
    cvt_storeA(p0, p1, Ah, Al, arow, ac);
    cvt_storeA(p2, p3, Ah + 32, Al + 32, arow, ac);
  }
  // prefetch A-step1 (cols 64..127)
  float4 nv0 = *(const float4*)(zrow +  64 + ac * 4);
  float4 nv1 = *(const float4*)(zrow +  80 + ac * 4);
  float4 nv2 = *(const float4*)(zrow +  96 + ac * 4);
  float4 nv3 = *(const float4*)(zrow + 112 + ac * 4);

  #pragma unroll
  for (int ks = 0; ks < 4; ++ks) {
    const int cur = (ks & 1) * 9216;
    const int nxt = 9216 - cur;
    // 2-deep prefetch of A(ks+2) (cols (ks+2)*64 ..)
    float4 fv0, fv1, fv2, fv3;
    if (ks < 2) {
      fv0 = *(const float4*)(zrow + (ks + 2) * 64 +      ac * 4);
      fv1 = *(const float4*)(zrow + (ks + 2) * 64 + 16 + ac * 4);
      fv2 = *(const float4*)(zrow + (ks + 2) * 64 + 32 + ac * 4);
      fv3 = *(const float4*)(zrow + (ks + 2) * 64 + 48 + ac * 4);
    }
    // B fragments for both 32-K sub-chunks (L2-hot)
    short8 bh0[4], bl0[4], bh1[4], bl1[4];
    #pragma unroll
    for (int nf = 0; nf < 4; ++nf) {
      bh0[nf] = *(const short8*)(bhbase + (2 * ks)     * 8192 + nf * 128);
      bl0[nf] = *(const short8*)(blbase + (2 * ks)     * 8192 + nf * 128);
      bh1[nf] = *(const short8*)(bhbase + (2 * ks + 1) * 8192 + nf * 128);
      bl1[nf] = *(const short8*)(blbase + (2 * ks + 1) * 8192 + nf * 128);
    }
    LGKM_BAR();
    __builtin_amdgcn_s_setprio(1);
    // sub-chunk 0 (K = ks*64 .. +31): hh, lh, hl  (order preserved per acc)
    #pragma unroll
    for (int mf = 0; mf < 4; ++mf) {
      const int ro = (wr * 64 + mf * 16 + l16) * 72 + lg * 8;
      short8 afh = *(const short8*)(&Ah[cur + ro]);
      short8 afl = *(const short8*)(&Al[cur + ro]);
      #pragma unroll
      for (int nf = 0; nf < 4; ++nf)
        acc[mf][nf] = __builtin_amdgcn_mfma_f32_16x16x32_bf16(afh, bh0[nf], acc[mf][nf], 0, 0, 0);
      #pragma unroll
      for (int nf = 0; nf < 4; ++nf)
        acc[mf][nf] = __builtin_amdgcn_mfma_f32_16x16x32_bf16(afl, bh0[nf], acc[mf][nf], 0, 0, 0);
      #pragma unroll
      for (int nf = 0; nf < 4; ++nf)
        acc[mf][nf] = __builtin_amdgcn_mfma_f32_16x16x32_bf16(afh, bl0[nf], acc[mf][nf], 0, 0, 0);
    }
    // sub-chunk 1 (K = ks*64+32 .. +63)
    #pragma unroll
    for (int mf = 0; mf < 4; ++mf) {
      const int ro = (wr * 64 + mf * 16 + l16) * 72 + 32 + lg * 8;
      short8 afh = *(const short8*)(&Ah[cur + ro]);
      short8 afl = *(const short8*)(&Al[cur + ro]);
      #pragma unroll
      for (int nf = 0; nf < 4; ++nf)
        acc[mf][nf] = __builtin_amdgcn_mfma_f32_16x16x32_bf16(afh, bh1[nf], acc[mf][nf], 0, 0, 0);
      #pragma unroll
      for (int nf = 0; nf < 4; ++nf)
        acc[mf][nf] = __builtin_amdgcn_mfma_f32_16x16x32_bf16(afl, bh1[nf], acc[mf][nf], 0, 0, 0);
      #pragma unroll
      for (int nf = 0; nf < 4; ++nf)
        acc[mf][nf] = __builtin_amdgcn_mfma_f32_16x16x32_bf16(afh, bl1[nf], acc[mf][nf], 0, 0, 0);
    }
    __builtin_amdgcn_s_setprio(0);
    // stage A(ks+1) from regs issued a full step ago; rotate prefetch
    if (ks < 3) {
      cvt_storeA(nv0, nv1, Ah + nxt,      Al + nxt,      arow, ac);
      cvt_storeA(nv2, nv3, Ah + nxt + 32, Al + nxt + 32, arow, ac);
      nv0 = fv0; nv1 = fv1; nv2 = fv2; nv3 = fv3;
    }
  }

  // ---- epilogue: +b1, write h1 (C/D: col=l16, row=lg*4+j), column stats ----
  float s1[4] = {0, 0, 0, 0}, s2[4] = {0, 0, 0, 0};
  #pragma unroll
  for (int nf = 0; nf < 4; ++nf) {
    int c = wc * 64 + nf * 16 + l16;
    float bb = b1[c];
    #pragma unroll
    for (int mf = 0; mf < 4; ++mf) {
      int rbase = n0 + wr * 64 + mf * 16 + lg * 4;
      #pragma unroll
      for (int j = 0; j < 4; ++j) {
        float v = acc[mf][nf][j] + bb;
        s1[nf] += v; s2[nf] += v * v;
        h1[(size_t)(rbase + j) * DDF + c] = v;
      }
    }
  }
  #pragma unroll
  for (int nf = 0; nf < 4; ++nf) {
    s1[nf] += __shfl_xor(s1[nf], 16); s1[nf] += __shfl_xor(s1[nf], 32);
    s2[nf] += __shfl_xor(s2[nf], 16); s2[nf] += __shfl_xor(s2[nf], 32);
  }
  __syncthreads();
  float* red1 = (float*)Ah;
  float* red2 = (float*)Al;
  if (l < 16) {
    #pragma unroll
    for (int nf = 0; nf < 4; ++nf) {
      red1[wr * 256 + wc * 64 + nf * 16 + l] = s1[nf];
      red2[wr * 256 + wc * 64 + nf * 16 + l] = s2[nf];
    }
  }
  __syncthreads();
  if (t < 256) {
    psum[blockIdx.x * 256 + t] = red1[t] + red1[256 + t];
    psq [blockIdx.x * 256 + t] = red2[t] + red2[256 + t];
  }
}

// ============ K2a: reduce 1024 partial rows -> 16x256 ============
__global__ __launch_bounds__(256) void k2a(const float* __restrict__ psum,
                                           const float* __restrict__ psq,
                                           float* __restrict__ tmp)
{
  int g = blockIdx.x & 7;
  const float* src = (blockIdx.x < 8) ? psum : psq;
  float acc = 0.f;
  #pragma unroll 8
  for (int r = 0; r < 128; ++r) acc += src[(g * 128 + r) * 256 + threadIdx.x];
  tmp[blockIdx.x * 256 + threadIdx.x] = acc;
}

// ============ K2b: finalize BN scale/shift ============
__global__ __launch_bounds__(256) void k2b(const float* __restrict__ tmp,
    const float* __restrict__ gam, const float* __restrict__ bet,
    float* __restrict__ scale, float* __restrict__ shift)
{
  int d = threadIdx.x;
  float s1 = 0.f, s2 = 0.f;
  #pragma unroll
  for (int g = 0; g < 8; ++g) { s1 += tmp[g*256+d]; s2 += tmp[(8+g)*256+d]; }
  float mu  = s1 * (1.0f / (float)NN);
  float var = s2 * (1.0f / (float)NN) - mu*mu;
  float inv = 1.0f / sqrtf(var + 1e-5f);
  float sc = gam[d] * inv;
  scale[d] = sc;
  shift[d] = bet[d] - mu*sc;
}

// ============ K3: BN+lrelu+GEMM2+softmax+std-filter, one wave per 64 rows ====
__global__ __launch_bounds__(256) void k3_gemm2(
    const float* __restrict__ h1, const float* __restrict__ W2,
    const float* __restrict__ b2, const float* __restrict__ scale,
    const float* __restrict__ shift, float* __restrict__ s_out,
    float* __restrict__ sf_out)
{
  __shared__ float ylds[4][64*32];
  const int t = threadIdx.x;
  const int w = t >> 6, l = t & 63;
  const int b = blockIdx.x * 2 + (w >> 1);
  const int half = w & 1;
  const int rowbase = b * MMN + half * 64;
  float* my = ylds[w];
  const int lx7 = l & 7;
  const int rsub = l >> 3;

  float acc[32];
  #pragma unroll
  for (int k = 0; k < 32; ++k) acc[k] = 0.f;

  for (int ch = 0; ch < 8; ++ch) {
    const float4 sc = *(const float4*)(scale + ch*32 + lx7*4);
    const float4 sh = *(const float4*)(shift + ch*32 + lx7*4);
    #pragma unroll
    for (int i = 0; i < 8; ++i) {
      int row = rsub + i*8;
      float4 v = *(const float4*)(h1 + (size_t)(rowbase + row)*DDF + ch*32 + lx7*4);
      float y0 = fmaf(v.x, sc.x, sh.x); y0 = y0 > 0.f ? y0 : 0.01f*y0;
      float y1 = fmaf(v.y, sc.y, sh.y); y1 = y1 > 0.f ? y1 : 0.01f*y1;
      float y2 = fmaf(v.z, sc.z, sh.z); y2 = y2 > 0.f ? y2 : 0.01f*y2;
      float y3 = fmaf(v.w, sc.w, sh.w); y3 = y3 > 0.f ? y3 : 0.01f*y3;
      *(float4*)(&my[row*32 + (lx7 ^ rsub)*4]) = make_float4(y0,y1,y2,y3);
    }
    #pragma unroll
    for (int d4 = 0; d4 < 8; ++d4) {
      float4 ya = *(const float4*)(&my[l*32 + (d4 ^ lx7)*4]);
      #pragma unroll
      for (int dd = 0; dd < 4; ++dd) {
        const float* w2r = W2 + (ch*32 + d4*4 + dd)*KKC;
        float a = (dd==0?ya.x: dd==1?ya.y: dd==2?ya.z: ya.w);
        #pragma unroll
        for (int k = 0; k < 32; ++k) acc[k] = fmaf(a, w2r[k], acc[k]);
      }
    }
  }
  #pragma unroll
  for (int k = 0; k < 32; ++k) acc[k] = (acc[k] + b2[k]) * 10.0f;
  float thr;
  {
    float m = acc[0];
    #pragma unroll
    for (int k = 1; k < 32; ++k) m = fmaxf(m, acc[k]);
    float sum = 0.f;
    #pragma unroll
    for (int k = 0; k < 32; ++k) { float e = expf(acc[k]-m); acc[k] = e; sum += e; }
    float inv = 1.0f/sum;
    float ssum = 0.f;
    #pragma unroll
    for (int k = 0; k < 32; ++k) { acc[k] *= inv; ssum += acc[k]; }
    float mean = ssum * (1.0f/32.0f);
    float var = 0.f;
    #pragma unroll
    for (int k = 0; k < 32; ++k) { float d = acc[k]-mean; var += d*d; }
    thr = sqrtf(var * (1.0f/31.0f)) + 0.03125f;
  }
  #pragma unroll
  for (int q = 0; q < 8; ++q)
    *(float4*)(&my[l*32 + (q ^ lx7)*4]) =
        make_float4(acc[q*4],acc[q*4+1],acc[q*4+2],acc[q*4+3]);
  #pragma unroll
  for (int i = 0; i < 8; ++i) {
    int fid = l + i*64;
    int row = fid >> 3, q = fid & 7;
    *(float4*)(s_out + (size_t)rowbase*KKC + fid*4) =
        *(const float4*)(&my[row*32 + (q ^ (row & 7))*4]);
  }
  #pragma unroll
  for (int k = 0; k < 32; ++k) acc[k] = acc[k] > thr ? acc[k] : 0.f;
  #pragma unroll
  for (int q = 0; q < 8; ++q)
    *(float4*)(&my[l*32 + (q ^ lx7)*4]) =
        make_float4(acc[q*4],acc[q*4+1],acc[q*4+2],acc[q*4+3]);
  #pragma unroll
  for (int i = 0; i < 8; ++i) {
    int fid = l + i*64;
    int row = fid >> 3, q = fid & 7;
    *(float4*)(sf_out + (size_t)rowbase*KKC + fid*4) =
        *(const float4*)(&my[row*32 + (q ^ (row & 7))*4]);
  }
}

// ============ K4: pooling + h_dense/h_flat/mask + zd + phat + g ============
// Chunk-loop barriers are LGKM-only: zd global-stores (no reader) stay in
// flight instead of being drained by __syncthreads' vmcnt(0) 16x.
__global__ __launch_bounds__(256) void k4_pool(
    const float* __restrict__ sf, const float* __restrict__ z,
    float* __restrict__ c_out, float* __restrict__ hdense,
    float* __restrict__ hflat, float* __restrict__ mask_out,
    float* __restrict__ zd, float* __restrict__ phat,
    const float* __restrict__ g, float* __restrict__ gout)
{
  __shared__ __align__(16) float sflds[128*32];   // 16 KB
  __shared__ __align__(16) float zlds[16*256];    // 16 KB
  __shared__ float redp[8*32];
  __shared__ float cred[32];

  const int t = threadIdx.x;
  const int w = t >> 6, l = t & 63;
  const int b = blockIdx.x;

  gout[b*256 + t] = g[b*256 + t];

  #pragma unroll
  for (int i = 0; i < 4; ++i) {
    int fid = t + i*256;
    *(float4*)(&sflds[fid*4]) = *(const float4*)(sf + (size_t)b*4096 + fid*4);
  }
  __syncthreads();
  {
    int k = t & 31, mg = t >> 5;
    float p = 0.f;
    #pragma unroll
    for (int m = 0; m < 16; ++m) p += sflds[(mg*16+m)*32 + k];
    redp[mg*32 + k] = p;
  }
  __syncthreads();
  if (t < 32) {
    float c = 0.f;
    #pragma unroll
    for (int g2 = 0; g2 < 8; ++g2) c += redp[g2*32 + t];
    cred[t] = c;
    c_out[b*32 + t] = c;
  }
  __syncthreads();
  {
    float cc = cred[t >> 3];
    float pv = cc / (cc + 1e-12f);
    int k1r = t >> 3;
    float4 ph;
    ph.x = (((t*4+0) & 31) == k1r) ? pv : 0.f;
    ph.y = (((t*4+1) & 31) == k1r) ? pv : 0.f;
    ph.z = (((t*4+2) & 31) == k1r) ? pv : 0.f;
    ph.w = (((t*4+3) & 31) == k1r) ? pv : 0.f;
    *(float4*)(phat + (size_t)b*1024 + t*4) = ph;
  }

  float acc[8][4];
  #pragma unroll
  for (int kk = 0; kk < 8; ++kk)
    #pragma unroll
    for (int j = 0; j < 4; ++j) acc[kk][j] = 0.f;

  for (int ch = 0; ch < 8; ++ch) {     // 16 rows per chunk
    #pragma unroll
    for (int i = 0; i < 4; ++i) {
      int fid = t + i*256;             // < 1024 float4s
      float4 v = *(const float4*)(z + (size_t)(b*128 + ch*16)*256 + fid*4);
      *(float4*)(&zlds[fid*4]) = v;
      *(float4*)(zd + (size_t)(b*128 + ch*16)*256 + fid*4) = v;
    }
    LGKM_BAR();                        // ds_writes visible; zd stores fly on
    #pragma unroll
    for (int mm = 0; mm < 16; ++mm) {
      float4 zv = *(const float4*)(&zlds[mm*256 + l*4]);
      float4 sa = *(const float4*)(&sflds[(ch*16+mm)*32 + w*8]);
      float4 sb = *(const float4*)(&sflds[(ch*16+mm)*32 + w*8 + 4]);
      float sv[8] = {sa.x,sa.y,sa.z,sa.w,sb.x,sb.y,sb.z,sb.w};
      #pragma unroll
      for (int kk = 0; kk < 8; ++kk) {
        acc[kk][0] = fmaf(sv[kk], zv.x, acc[kk][0]);
        acc[kk][1] = fmaf(sv[kk], zv.y, acc[kk][1]);
        acc[kk][2] = fmaf(sv[kk], zv.z, acc[kk][2]);
        acc[kk][3] = fmaf(sv[kk], zv.w, acc[kk][3]);
      }
    }
    LGKM_BAR();                        // all waves' ds_reads retired
  }
  float asum[8], mkarr[8];
  #pragma unroll
  for (int kk = 0; kk < 8; ++kk) {
    float wnv = 1.0f / fmaxf(cred[w*8+kk], 1e-12f);
    acc[kk][0]*=wnv; acc[kk][1]*=wnv; acc[kk][2]*=wnv; acc[kk][3]*=wnv;
    asum[kk] = fabsf(acc[kk][0])+fabsf(acc[kk][1])+fabsf(acc[kk][2])+fabsf(acc[kk][3]);
  }
  #pragma unroll
  for (int kk = 0; kk < 8; ++kk) {
    float a = asum[kk];
    #pragma unroll
    for (int off = 1; off < 64; off <<= 1) a += __shfl_xor(a, off);
    asum[kk] = a;
  }
  #pragma unroll
  for (int kk = 0; kk < 8; ++kk) {
    int krow = b*32 + w*8 + kk;
    float mk = asum[kk] > 0.f ? 1.0f : 0.0f;
    mkarr[kk] = mk;
    float h0=acc[kk][0], h1v=acc[kk][1], h2=acc[kk][2], h3=acc[kk][3];
    *(float4*)(hdense + (size_t)krow*256 + l*4) = make_float4(h0,h1v,h2,h3);
    *(float4*)(hflat  + (size_t)krow*256 + l*4) =
        make_float4(h0*mk,h1v*mk,h2*mk,h3*mk);
  }
  if (l == 0) {
    #pragma unroll
    for (int kk = 0; kk < 8; ++kk) mask_out[b*32 + w*8 + kk] = mkarr[kk];
  }
}

// ============ K4b: p = (hflat/||hflat||) @ Un^T  (hflat L3-hot) ============
__global__ __launch_bounds__(256) void k4b_p(
    const float* __restrict__ hflat, const float* __restrict__ Un,
    float* __restrict__ p_out)
{
  __shared__ float hl[32*260];
  __shared__ float ul[32*256];
  const int t = threadIdx.x;
  const int b = blockIdx.x;

  #pragma unroll
  for (int i = 0; i < 8; ++i) {
    int fid = t + i*256;
    int row = fid >> 6, c4 = fid & 63;
    *(float4*)(&hl[row*260 + c4*4]) =
        *(const float4*)(hflat + (size_t)b*8192 + fid*4);
    *(float4*)(&ul[fid*4]) = *(const float4*)(Un + fid*4);
  }
  __syncthreads();
  {
    const int k = t & 31, k2 = (t >> 5) * 4;
    float p0=0.f, p1=0.f, p2=0.f, p3=0.f, qq=0.f;
    #pragma unroll 8
    for (int d4 = 0; d4 < 64; ++d4) {
      float4 hv = *(const float4*)(&hl[k*260 + d4*4]);
      qq = fmaf(hv.x,hv.x,fmaf(hv.y,hv.y,fmaf(hv.z,hv.z,fmaf(hv.w,hv.w,qq))));
      float4 u0 = *(const float4*)(&ul[(k2+0)*256 + d4*4]);
      float4 u1 = *(const float4*)(&ul[(k2+1)*256 + d4*4]);
      float4 u2 = *(const float4*)(&ul[(k2+2)*256 + d4*4]);
      float4 u3 = *(const float4*)(&ul[(k2+3)*256 + d4*4]);
      p0 = fmaf(hv.x,u0.x,fmaf(hv.y,u0.y,fmaf(hv.z,u0.z,fmaf(hv.w,u0.w,p0))));
      p1 = fmaf(hv.x,u1.x,fmaf(hv.y,u1.y,fmaf(hv.z,u1.z,fmaf(hv.w,u1.w,p1))));
      p2 = fmaf(hv.x,u2.x,fmaf(hv.y,u2.y,fmaf(hv.z,u2.z,fmaf(hv.w,u2.w,p2))));
      p3 = fmaf(hv.x,u3.x,fmaf(hv.y,u3.y,fmaf(hv.z,u3.z,fmaf(hv.w,u3.w,p3))));
    }
    float inv = 1.0f / fmaxf(sqrtf(qq), 1e-12f);
    *(float4*)(p_out + (size_t)(b*32 + k)*32 + k2) =
        make_float4(p0*inv, p1*inv, p2*inv, p3*inv);
  }
}

// ============ K5a: partial sums of h_dense over b ============
__global__ __launch_bounds__(256) void k5a(const float* __restrict__ hdense,
                                           float* __restrict__ part)
{
  int k = blockIdx.x & 31, seg = blockIdx.x >> 5;
  int t = threadIdx.x;
  float s = 0.f;
  #pragma unroll 4
  for (int i = 0; i < 128; ++i) {
    int b = seg*128 + i;
    s += hdense[(size_t)(b*32 + k)*256 + t];
  }
  part[blockIdx.x*256 + t] = s;
}

// ============ K5b: sizes (reshape semantics!) + centroids + U_new ============
__global__ __launch_bounds__(256) void k5b(const float* __restrict__ part,
    const float* __restrict__ maskf, const float* __restrict__ U,
    float* __restrict__ Unew)
{
  __shared__ float r4[4];
  int k = blockIdx.x, t = threadIdx.x;
  float4 mv = *(const float4*)(maskf + k*1024 + t*4);
  float m4 = mv.x + mv.y + mv.z + mv.w;
  #pragma unroll
  for (int off = 1; off < 64; off <<= 1) m4 += __shfl_xor(m4, off);
  if ((t & 63) == 0) r4[t >> 6] = m4;
  __syncthreads();
  float sizes = r4[0] + r4[1] + r4[2] + r4[3];
  float csum = 0.f;
  #pragma unroll
  for (int g = 0; g < 8; ++g) csum += part[(g*32 + k)*256 + t];
  float cent = csum / (sizes + 1e-10f);
  Unew[k*256 + t] = 0.99f * U[k*256 + t] + 0.01f * cent;
}

extern "C" void kernel_launch(void* const* d_in, const int* in_sizes, int n_in,
                              void* d_out, int out_size, void* d_ws, size_t ws_size,
                              hipStream_t stream)
{
  const float* z   = (const float*)d_in[0];
  const float* g   = (const float*)d_in[1];
  const float* W1  = (const float*)d_in[3];
  const float* b1  = (const float*)d_in[4];
  const float* gam = (const float*)d_in[5];
  const float* bet = (const float*)d_in[6];
  const float* W2  = (const float*)d_in[7];
  const float* b2  = (const float*)d_in[8];
  const float* U   = (const float*)d_in[9];
  float* out = (float*)d_out;
  float* ws  = (float*)d_ws;

  float* h1 = out + OFF_ZD;                         // stash h1 in z_dense region
  unsigned short* preh = (unsigned short*)(out + OFF_S);  // W1T scratch in s region
  unsigned short* prel = preh + 65536;              // (k3 overwrites s later)

  k0_prep<<<40, 256, 0, stream>>>(W1, U, preh, prel, ws+WS_UN);
  k1_gemm1<<<1024, 512, 0, stream>>>(z, preh, prel, b1, h1, ws+WS_PSUM, ws+WS_PSQ);
  k2a<<<16, 256, 0, stream>>>(ws+WS_PSUM, ws+WS_PSQ, ws+WS_TMP);
  k2b<<<1, 256, 0, stream>>>(ws+WS_TMP, gam, bet, ws+WS_SCALE, ws+WS_SHIFT);
  k3_gemm2<<<512, 256, 0, stream>>>(h1, W2, b2, ws+WS_SCALE, ws+WS_SHIFT,
                                    out+OFF_S, ws+WS_SF);
  k4_pool<<<1024, 256, 0, stream>>>(ws+WS_SF, z, ws+WS_C,
                                    out+OFF_HDENSE, out+OFF_HFLAT,
                                    out+OFF_MASK, out+OFF_ZD,
                                    out+OFF_PHAT, g, out+OFF_G);
  k4b_p<<<1024, 256, 0, stream>>>(out+OFF_HFLAT, ws+WS_UN, out+OFF_P);
  k5a<<<256, 256, 0, stream>>>(out+OFF_HDENSE, ws+WS_PART);
  k5b<<<32, 256, 0, stream>>>(ws+WS_PART, out+OFF_MASK, U, out+OFF_UNEW);
}

// Round 13
// 276.207 us; speedup vs baseline: 1.0340x; 1.0340x over previous
//
#include <hip/hip_runtime.h>
#include <math.h>

#define NN 131072
#define BBG 1024
#define MMN 128
#define DDF 256
#define KKC 32

// ---- d_out offsets (floats), concatenated in reference return order ----
#define OFF_S      0
#define OFF_HFLAT  4194304
#define OFF_HDENSE 12582912
#define OFF_P      20971520
#define OFF_PHAT   22020096
#define OFF_ZD     23068672
#define OFF_G      56623104
#define OFF_MASK   56885248
#define OFF_UNEW   56918016

// ---- ws offsets (floats) ----
#define WS_PSUM  0          // [1024][256]
#define WS_PSQ   524288     // [1024][256]
#define WS_TMP   1048576    // [16][256]
#define WS_SCALE 1052672    // [256]
#define WS_SHIFT 1052928    // [256]
#define WS_UN    1053184    // [32][256]
#define WS_SF    1061376    // [N][32]
#define WS_C     5255680    // [B][32]
#define WS_PART  5288448    // [8*32][256]

typedef __attribute__((ext_vector_type(8))) short short8;
typedef __attribute__((ext_vector_type(4))) float f32x4;

// raw barrier with lgkm-only drain: global loads/stores stay in flight (T4)
#define LGKM_BAR() do { asm volatile("s_waitcnt lgkmcnt(0)" ::: "memory"); \
  __builtin_amdgcn_s_barrier(); __builtin_amdgcn_sched_barrier(0); } while (0)

__device__ __forceinline__ unsigned short f2bf(float x) {
  unsigned u = __float_as_uint(x);
  u += 0x7fffu + ((u >> 16) & 1u);
  return (unsigned short)(u >> 16);
}
__device__ __forceinline__ float bf2f(unsigned short h) {
  return __uint_as_float(((unsigned)h) << 16);
}

// ============ K0: W1 -> blocked bf16 hi/lo  +  Un = U/||U|| ============
__global__ __launch_bounds__(256) void k0_prep(const float* __restrict__ W1,
    const float* __restrict__ U, unsigned short* __restrict__ preh,
    unsigned short* __restrict__ prel, float* __restrict__ Un)
{
  if (blockIdx.x < 32) {
    int tid = blockIdx.x * 256 + threadIdx.x;   // < 8192
    int n = tid & 255, kq = tid >> 8;           // kq in [0,32): k = kq*8 + j
    short8 hv, lv;
    #pragma unroll
    for (int j = 0; j < 8; ++j) {
      float v = W1[(kq * 8 + j) * DDF + n];
      unsigned short hb = f2bf(v);
      hv[j] = (short)hb;
      lv[j] = (short)f2bf(v - bf2f(hb));
    }
    int base = (kq >> 2) * 8192 + (kq & 3) * 2048 + n * 8;
    *(short8*)(preh + base) = hv;
    *(short8*)(prel + base) = lv;
  } else {
    int k = (blockIdx.x - 32) * 4 + (threadIdx.x >> 6);  // 32 rows
    int l = threadIdx.x & 63;
    float4 u = *(const float4*)(U + k*256 + l*4);
    float ss = u.x*u.x + u.y*u.y + u.z*u.z + u.w*u.w;
    #pragma unroll
    for (int off = 32; off >= 1; off >>= 1) ss += __shfl_xor(ss, off);
    float inv = 1.0f / fmaxf(sqrtf(ss), 1e-12f);
    *(float4*)(Un + k*256 + l*4) = make_float4(u.x*inv, u.y*inv, u.z*inv, u.w*inv);
  }
}

// ============ K1: h1 = z@W1 + b1 via 3-term bf16x2 MFMA + column stats ========
// R11 structure (BK=32, LGKM_BAR, 2-deep z prefetch) + 1-step B prefetch:
// B(ks+1) issued right AFTER the barrier so its L2 latency hides under the
// 48-MFMA phase; phase ks+1 starts with B already in regs.
__device__ __forceinline__ void cvt_storeA(float4 za, float4 zb,
    unsigned short* AhB, unsigned short* AlB, int arow, int ac)
{
  unsigned short h0 = f2bf(za.x), h1v = f2bf(za.y), h2 = f2bf(za.z), h3 = f2bf(za.w);
  unsigned short g0 = f2bf(zb.x), g1 = f2bf(zb.y), g2 = f2bf(zb.z), g3 = f2bf(zb.w);
  uint2 hA = make_uint2((unsigned)h0 | ((unsigned)h1v << 16),
                        (unsigned)h2 | ((unsigned)h3 << 16));
  uint2 hB = make_uint2((unsigned)g0 | ((unsigned)g1 << 16),
                        (unsigned)g2 | ((unsigned)g3 << 16));
  uint2 lA = make_uint2((unsigned)f2bf(za.x - bf2f(h0)) | ((unsigned)f2bf(za.y - bf2f(h1v)) << 16),
                        (unsigned)f2bf(za.z - bf2f(h2)) | ((unsigned)f2bf(za.w - bf2f(h3)) << 16));
  uint2 lB = make_uint2((unsigned)f2bf(zb.x - bf2f(g0)) | ((unsigned)f2bf(zb.y - bf2f(g1)) << 16),
                        (unsigned)f2bf(zb.z - bf2f(g2)) | ((unsigned)f2bf(zb.w - bf2f(g3)) << 16));
  *(uint2*)(AhB + arow * 40 + ac * 4)      = hA;
  *(uint2*)(AhB + arow * 40 + 16 + ac * 4) = hB;
  *(uint2*)(AlB + arow * 40 + ac * 4)      = lA;
  *(uint2*)(AlB + arow * 40 + 16 + ac * 4) = lB;
}

__global__ __launch_bounds__(512) void k1_gemm1(
    const float* __restrict__ z, const unsigned short* __restrict__ preh,
    const unsigned short* __restrict__ prel, const float* __restrict__ b1,
    float* __restrict__ h1, float* __restrict__ psum, float* __restrict__ psq)
{
  __shared__ __attribute__((aligned(16))) unsigned short Ah[2 * 128 * 40];
  __shared__ __attribute__((aligned(16))) unsigned short Al[2 * 128 * 40];

  const int t = threadIdx.x;
  const int l = t & 63;
  const int w = t >> 6;
  const int wr = w >> 2;
  const int wc = w & 3;
  const int lg = l >> 4;
  const int l16 = l & 15;
  const int n0 = blockIdx.x * 128;

  f32x4 acc[4][4];
  #pragma unroll
  for (int i = 0; i < 4; ++i)
    #pragma unroll
    for (int j = 0; j < 4; ++j) acc[i][j] = (f32x4)0.0f;

  const int arow = t >> 2, ac = t & 3;
  const float* zrow = z + (size_t)(n0 + arow) * DDF;
  const unsigned short* bhbase = preh + lg * 2048 + wc * 512 + l16 * 8;
  const unsigned short* blbase = prel + lg * 2048 + wc * 512 + l16 * 8;

  {
    float4 za = *(const float4*)(zrow + ac * 4);
    float4 zb = *(const float4*)(zrow + 16 + ac * 4);
    cvt_storeA(za, zb, Ah, Al, arow, ac);
  }
  float4 zaN = *(const float4*)(zrow + 32 + ac * 4);
  float4 zbN = *(const float4*)(zrow + 48 + ac * 4);
  // B(0) prefetch (prologue)
  short8 bfh[4], bfl[4];
  #pragma unroll
  for (int nf = 0; nf < 4; ++nf) {
    bfh[nf] = *(const short8*)(bhbase + nf * 128);
    bfl[nf] = *(const short8*)(blbase + nf * 128);
  }

  #pragma unroll
  for (int ks = 0; ks < 8; ++ks) {
    const int cur = (ks & 1) * 5120;
    const int nxt = 5120 - cur;
    // 2-deep z prefetch
    float4 zaF, zbF;
    if (ks < 6) {
      zaF = *(const float4*)(zrow + (ks + 2) * 32 + ac * 4);
      zbF = *(const float4*)(zrow + (ks + 2) * 32 + 16 + ac * 4);
    }
    LGKM_BAR();
    // issue B(ks+1) right after the barrier: L2 latency hides under MFMA
    short8 bfhN[4], bflN[4];
    if (ks < 7) {
      #pragma unroll
      for (int nf = 0; nf < 4; ++nf) {
        bfhN[nf] = *(const short8*)(bhbase + (ks + 1) * 8192 + nf * 128);
        bflN[nf] = *(const short8*)(blbase + (ks + 1) * 8192 + nf * 128);
      }
    }
    __builtin_amdgcn_s_setprio(1);
    #pragma unroll
    for (int mf = 0; mf < 4; ++mf) {
      const int ar = wr * 64 + mf * 16 + l16;
      short8 afh = *(const short8*)(&Ah[cur + ar * 40 + lg * 8]);
      short8 afl = *(const short8*)(&Al[cur + ar * 40 + lg * 8]);
      #pragma unroll
      for (int nf = 0; nf < 4; ++nf)
        acc[mf][nf] = __builtin_amdgcn_mfma_f32_16x16x32_bf16(afh, bfh[nf], acc[mf][nf], 0, 0, 0);
      #pragma unroll
      for (int nf = 0; nf < 4; ++nf)
        acc[mf][nf] = __builtin_amdgcn_mfma_f32_16x16x32_bf16(afl, bfh[nf], acc[mf][nf], 0, 0, 0);
      #pragma unroll
      for (int nf = 0; nf < 4; ++nf)
        acc[mf][nf] = __builtin_amdgcn_mfma_f32_16x16x32_bf16(afh, bfl[nf], acc[mf][nf], 0, 0, 0);
    }
    __builtin_amdgcn_s_setprio(0);
    if (ks < 7) {
      cvt_storeA(zaN, zbN, Ah + nxt, Al + nxt, arow, ac);
      zaN = zaF; zbN = zbF;
      #pragma unroll
      for (int nf = 0; nf < 4; ++nf) { bfh[nf] = bfhN[nf]; bfl[nf] = bflN[nf]; }
    }
  }

  float s1[4] = {0, 0, 0, 0}, s2[4] = {0, 0, 0, 0};
  #pragma unroll
  for (int nf = 0; nf < 4; ++nf) {
    int c = wc * 64 + nf * 16 + l16;
    float bb = b1[c];
    #pragma unroll
    for (int mf = 0; mf < 4; ++mf) {
      int rbase = n0 + wr * 64 + mf * 16 + lg * 4;
      #pragma unroll
      for (int j = 0; j < 4; ++j) {
        float v = acc[mf][nf][j] + bb;
        s1[nf] += v; s2[nf] += v * v;
        h1[(size_t)(rbase + j) * DDF + c] = v;
      }
    }
  }
  #pragma unroll
  for (int nf = 0; nf < 4; ++nf) {
    s1[nf] += __shfl_xor(s1[nf], 16); s1[nf] += __shfl_xor(s1[nf], 32);
    s2[nf] += __shfl_xor(s2[nf], 16); s2[nf] += __shfl_xor(s2[nf], 32);
  }
  __syncthreads();
  float* red1 = (float*)Ah;
  float* red2 = (float*)Al;
  if (l < 16) {
    #pragma unroll
    for (int nf = 0; nf < 4; ++nf) {
      red1[wr * 256 + wc * 64 + nf * 16 + l] = s1[nf];
      red2[wr * 256 + wc * 64 + nf * 16 + l] = s2[nf];
    }
  }
  __syncthreads();
  if (t < 256) {
    psum[blockIdx.x * 256 + t] = red1[t] + red1[256 + t];
    psq [blockIdx.x * 256 + t] = red2[t] + red2[256 + t];
  }
}

// ============ K2a: reduce 1024 partial rows -> 16x256 ============
__global__ __launch_bounds__(256) void k2a(const float* __restrict__ psum,
                                           const float* __restrict__ psq,
                                           float* __restrict__ tmp)
{
  int g = blockIdx.x & 7;
  const float* src = (blockIdx.x < 8) ? psum : psq;
  float acc = 0.f;
  #pragma unroll 8
  for (int r = 0; r < 128; ++r) acc += src[(g * 128 + r) * 256 + threadIdx.x];
  tmp[blockIdx.x * 256 + threadIdx.x] = acc;
}

// ============ K2b: finalize BN scale/shift ============
__global__ __launch_bounds__(256) void k2b(const float* __restrict__ tmp,
    const float* __restrict__ gam, const float* __restrict__ bet,
    float* __restrict__ scale, float* __restrict__ shift)
{
  int d = threadIdx.x;
  float s1 = 0.f, s2 = 0.f;
  #pragma unroll
  for (int g = 0; g < 8; ++g) { s1 += tmp[g*256+d]; s2 += tmp[(8+g)*256+d]; }
  float mu  = s1 * (1.0f / (float)NN);
  float var = s2 * (1.0f / (float)NN) - mu*mu;
  float inv = 1.0f / sqrtf(var + 1e-5f);
  float sc = gam[d] * inv;
  scale[d] = sc;
  shift[d] = bet[d] - mu*sc;
}

// ============ K3: BN+lrelu+GEMM2+softmax+std-filter, one wave per 64 rows ====
__global__ __launch_bounds__(256) void k3_gemm2(
    const float* __restrict__ h1, const float* __restrict__ W2,
    const float* __restrict__ b2, const float* __restrict__ scale,
    const float* __restrict__ shift, float* __restrict__ s_out,
    float* __restrict__ sf_out)
{
  __shared__ float ylds[4][64*32];
  const int t = threadIdx.x;
  const int w = t >> 6, l = t & 63;
  const int b = blockIdx.x * 2 + (w >> 1);
  const int half = w & 1;
  const int rowbase = b * MMN + half * 64;
  float* my = ylds[w];
  const int lx7 = l & 7;
  const int rsub = l >> 3;

  float acc[32];
  #pragma unroll
  for (int k = 0; k < 32; ++k) acc[k] = 0.f;

  for (int ch = 0; ch < 8; ++ch) {
    const float4 sc = *(const float4*)(scale + ch*32 + lx7*4);
    const float4 sh = *(const float4*)(shift + ch*32 + lx7*4);
    #pragma unroll
    for (int i = 0; i < 8; ++i) {
      int row = rsub + i*8;
      float4 v = *(const float4*)(h1 + (size_t)(rowbase + row)*DDF + ch*32 + lx7*4);
      float y0 = fmaf(v.x, sc.x, sh.x); y0 = y0 > 0.f ? y0 : 0.01f*y0;
      float y1 = fmaf(v.y, sc.y, sh.y); y1 = y1 > 0.f ? y1 : 0.01f*y1;
      float y2 = fmaf(v.z, sc.z, sh.z); y2 = y2 > 0.f ? y2 : 0.01f*y2;
      float y3 = fmaf(v.w, sc.w, sh.w); y3 = y3 > 0.f ? y3 : 0.01f*y3;
      *(float4*)(&my[row*32 + (lx7 ^ rsub)*4]) = make_float4(y0,y1,y2,y3);
    }
    #pragma unroll
    for (int d4 = 0; d4 < 8; ++d4) {
      float4 ya = *(const float4*)(&my[l*32 + (d4 ^ lx7)*4]);
      #pragma unroll
      for (int dd = 0; dd < 4; ++dd) {
        const float* w2r = W2 + (ch*32 + d4*4 + dd)*KKC;
        float a = (dd==0?ya.x: dd==1?ya.y: dd==2?ya.z: ya.w);
        #pragma unroll
        for (int k = 0; k < 32; ++k) acc[k] = fmaf(a, w2r[k], acc[k]);
      }
    }
  }
  #pragma unroll
  for (int k = 0; k < 32; ++k) acc[k] = (acc[k] + b2[k]) * 10.0f;
  float thr;
  {
    float m = acc[0];
    #pragma unroll
    for (int k = 1; k < 32; ++k) m = fmaxf(m, acc[k]);
    float sum = 0.f;
    #pragma unroll
    for (int k = 0; k < 32; ++k) { float e = expf(acc[k]-m); acc[k] = e; sum += e; }
    float inv = 1.0f/sum;
    float ssum = 0.f;
    #pragma unroll
    for (int k = 0; k < 32; ++k) { acc[k] *= inv; ssum += acc[k]; }
    float mean = ssum * (1.0f/32.0f);
    float var = 0.f;
    #pragma unroll
    for (int k = 0; k < 32; ++k) { float d = acc[k]-mean; var += d*d; }
    thr = sqrtf(var * (1.0f/31.0f)) + 0.03125f;
  }
  #pragma unroll
  for (int q = 0; q < 8; ++q)
    *(float4*)(&my[l*32 + (q ^ lx7)*4]) =
        make_float4(acc[q*4],acc[q*4+1],acc[q*4+2],acc[q*4+3]);
  #pragma unroll
  for (int i = 0; i < 8; ++i) {
    int fid = l + i*64;
    int row = fid >> 3, q = fid & 7;
    *(float4*)(s_out + (size_t)rowbase*KKC + fid*4) =
        *(const float4*)(&my[row*32 + (q ^ (row & 7))*4]);
  }
  #pragma unroll
  for (int k = 0; k < 32; ++k) acc[k] = acc[k] > thr ? acc[k] : 0.f;
  #pragma unroll
  for (int q = 0; q < 8; ++q)
    *(float4*)(&my[l*32 + (q ^ lx7)*4]) =
        make_float4(acc[q*4],acc[q*4+1],acc[q*4+2],acc[q*4+3]);
  #pragma unroll
  for (int i = 0; i < 8; ++i) {
    int fid = l + i*64;
    int row = fid >> 3, q = fid & 7;
    *(float4*)(sf_out + (size_t)rowbase*KKC + fid*4) =
        *(const float4*)(&my[row*32 + (q ^ (row & 7))*4]);
  }
}

// ============ K4: pooling + h_dense/h_flat/mask + zd + phat + g ============
// Chunk-loop barriers are LGKM-only: zd global-stores (no reader) stay in
// flight instead of being drained by __syncthreads' vmcnt(0) 16x.
__global__ __launch_bounds__(256) void k4_pool(
    const float* __restrict__ sf, const float* __restrict__ z,
    float* __restrict__ c_out, float* __restrict__ hdense,
    float* __restrict__ hflat, float* __restrict__ mask_out,
    float* __restrict__ zd, float* __restrict__ phat,
    const float* __restrict__ g, float* __restrict__ gout)
{
  __shared__ __align__(16) float sflds[128*32];   // 16 KB
  __shared__ __align__(16) float zlds[16*256];    // 16 KB
  __shared__ float redp[8*32];
  __shared__ float cred[32];

  const int t = threadIdx.x;
  const int w = t >> 6, l = t & 63;
  const int b = blockIdx.x;

  gout[b*256 + t] = g[b*256 + t];

  #pragma unroll
  for (int i = 0; i < 4; ++i) {
    int fid = t + i*256;
    *(float4*)(&sflds[fid*4]) = *(const float4*)(sf + (size_t)b*4096 + fid*4);
  }
  __syncthreads();
  {
    int k = t & 31, mg = t >> 5;
    float p = 0.f;
    #pragma unroll
    for (int m = 0; m < 16; ++m) p += sflds[(mg*16+m)*32 + k];
    redp[mg*32 + k] = p;
  }
  __syncthreads();
  if (t < 32) {
    float c = 0.f;
    #pragma unroll
    for (int g2 = 0; g2 < 8; ++g2) c += redp[g2*32 + t];
    cred[t] = c;
    c_out[b*32 + t] = c;
  }
  __syncthreads();
  {
    float cc = cred[t >> 3];
    float pv = cc / (cc + 1e-12f);
    int k1r = t >> 3;
    float4 ph;
    ph.x = (((t*4+0) & 31) == k1r) ? pv : 0.f;
    ph.y = (((t*4+1) & 31) == k1r) ? pv : 0.f;
    ph.z = (((t*4+2) & 31) == k1r) ? pv : 0.f;
    ph.w = (((t*4+3) & 31) == k1r) ? pv : 0.f;
    *(float4*)(phat + (size_t)b*1024 + t*4) = ph;
  }

  float acc[8][4];
  #pragma unroll
  for (int kk = 0; kk < 8; ++kk)
    #pragma unroll
    for (int j = 0; j < 4; ++j) acc[kk][j] = 0.f;

  for (int ch = 0; ch < 8; ++ch) {     // 16 rows per chunk
    #pragma unroll
    for (int i = 0; i < 4; ++i) {
      int fid = t + i*256;             // < 1024 float4s
      float4 v = *(const float4*)(z + (size_t)(b*128 + ch*16)*256 + fid*4);
      *(float4*)(&zlds[fid*4]) = v;
      *(float4*)(zd + (size_t)(b*128 + ch*16)*256 + fid*4) = v;
    }
    LGKM_BAR();                        // ds_writes visible; zd stores fly on
    #pragma unroll
    for (int mm = 0; mm < 16; ++mm) {
      float4 zv = *(const float4*)(&zlds[mm*256 + l*4]);
      float4 sa = *(const float4*)(&sflds[(ch*16+mm)*32 + w*8]);
      float4 sb = *(const float4*)(&sflds[(ch*16+mm)*32 + w*8 + 4]);
      float sv[8] = {sa.x,sa.y,sa.z,sa.w,sb.x,sb.y,sb.z,sb.w};
      #pragma unroll
      for (int kk = 0; kk < 8; ++kk) {
        acc[kk][0] = fmaf(sv[kk], zv.x, acc[kk][0]);
        acc[kk][1] = fmaf(sv[kk], zv.y, acc[kk][1]);
        acc[kk][2] = fmaf(sv[kk], zv.z, acc[kk][2]);
        acc[kk][3] = fmaf(sv[kk], zv.w, acc[kk][3]);
      }
    }
    LGKM_BAR();                        // all waves' ds_reads retired
  }
  float asum[8], mkarr[8];
  #pragma unroll
  for (int kk = 0; kk < 8; ++kk) {
    float wnv = 1.0f / fmaxf(cred[w*8+kk], 1e-12f);
    acc[kk][0]*=wnv; acc[kk][1]*=wnv; acc[kk][2]*=wnv; acc[kk][3]*=wnv;
    asum[kk] = fabsf(acc[kk][0])+fabsf(acc[kk][1])+fabsf(acc[kk][2])+fabsf(acc[kk][3]);
  }
  #pragma unroll
  for (int kk = 0; kk < 8; ++kk) {
    float a = asum[kk];
    #pragma unroll
    for (int off = 1; off < 64; off <<= 1) a += __shfl_xor(a, off);
    asum[kk] = a;
  }
  #pragma unroll
  for (int kk = 0; kk < 8; ++kk) {
    int krow = b*32 + w*8 + kk;
    float mk = asum[kk] > 0.f ? 1.0f : 0.0f;
    mkarr[kk] = mk;
    float h0=acc[kk][0], h1v=acc[kk][1], h2=acc[kk][2], h3=acc[kk][3];
    *(float4*)(hdense + (size_t)krow*256 + l*4) = make_float4(h0,h1v,h2,h3);
    *(float4*)(hflat  + (size_t)krow*256 + l*4) =
        make_float4(h0*mk,h1v*mk,h2*mk,h3*mk);
  }
  if (l == 0) {
    #pragma unroll
    for (int kk = 0; kk < 8; ++kk) mask_out[b*32 + w*8 + kk] = mkarr[kk];
  }
}

// ============ K4b: p = (hflat/||hflat||) @ Un^T  (hflat L3-hot) ============
__global__ __launch_bounds__(256) void k4b_p(
    const float* __restrict__ hflat, const float* __restrict__ Un,
    float* __restrict__ p_out)
{
  __shared__ float hl[32*260];
  __shared__ float ul[32*256];
  const int t = threadIdx.x;
  const int b = blockIdx.x;

  #pragma unroll
  for (int i = 0; i < 8; ++i) {
    int fid = t + i*256;
    int row = fid >> 6, c4 = fid & 63;
    *(float4*)(&hl[row*260 + c4*4]) =
        *(const float4*)(hflat + (size_t)b*8192 + fid*4);
    *(float4*)(&ul[fid*4]) = *(const float4*)(Un + fid*4);
  }
  __syncthreads();
  {
    const int k = t & 31, k2 = (t >> 5) * 4;
    float p0=0.f, p1=0.f, p2=0.f, p3=0.f, qq=0.f;
    #pragma unroll 8
    for (int d4 = 0; d4 < 64; ++d4) {
      float4 hv = *(const float4*)(&hl[k*260 + d4*4]);
      qq = fmaf(hv.x,hv.x,fmaf(hv.y,hv.y,fmaf(hv.z,hv.z,fmaf(hv.w,hv.w,qq))));
      float4 u0 = *(const float4*)(&ul[(k2+0)*256 + d4*4]);
      float4 u1 = *(const float4*)(&ul[(k2+1)*256 + d4*4]);
      float4 u2 = *(const float4*)(&ul[(k2+2)*256 + d4*4]);
      float4 u3 = *(const float4*)(&ul[(k2+3)*256 + d4*4]);
      p0 = fmaf(hv.x,u0.x,fmaf(hv.y,u0.y,fmaf(hv.z,u0.z,fmaf(hv.w,u0.w,p0))));
      p1 = fmaf(hv.x,u1.x,fmaf(hv.y,u1.y,fmaf(hv.z,u1.z,fmaf(hv.w,u1.w,p1))));
      p2 = fmaf(hv.x,u2.x,fmaf(hv.y,u2.y,fmaf(hv.z,u2.z,fmaf(hv.w,u2.w,p2))));
      p3 = fmaf(hv.x,u3.x,fmaf(hv.y,u3.y,fmaf(hv.z,u3.z,fmaf(hv.w,u3.w,p3))));
    }
    float inv = 1.0f / fmaxf(sqrtf(qq), 1e-12f);
    *(float4*)(p_out + (size_t)(b*32 + k)*32 + k2) =
        make_float4(p0*inv, p1*inv, p2*inv, p3*inv);
  }
}

// ============ K5a: partial sums of h_dense over b ============
__global__ __launch_bounds__(256) void k5a(const float* __restrict__ hdense,
                                           float* __restrict__ part)
{
  int k = blockIdx.x & 31, seg = blockIdx.x >> 5;
  int t = threadIdx.x;
  float s = 0.f;
  #pragma unroll 4
  for (int i = 0; i < 128; ++i) {
    int b = seg*128 + i;
    s += hdense[(size_t)(b*32 + k)*256 + t];
  }
  part[blockIdx.x*256 + t] = s;
}

// ============ K5b: sizes (reshape semantics!) + centroids + U_new ============
__global__ __launch_bounds__(256) void k5b(const float* __restrict__ part,
    const float* __restrict__ maskf, const float* __restrict__ U,
    float* __restrict__ Unew)
{
  __shared__ float r4[4];
  int k = blockIdx.x, t = threadIdx.x;
  float4 mv = *(const float4*)(maskf + k*1024 + t*4);
  float m4 = mv.x + mv.y + mv.z + mv.w;
  #pragma unroll
  for (int off = 1; off < 64; off <<= 1) m4 += __shfl_xor(m4, off);
  if ((t & 63) == 0) r4[t >> 6] = m4;
  __syncthreads();
  float sizes = r4[0] + r4[1] + r4[2] + r4[3];
  float csum = 0.f;
  #pragma unroll
  for (int g = 0; g < 8; ++g) csum += part[(g*32 + k)*256 + t];
  float cent = csum / (sizes + 1e-10f);
  Unew[k*256 + t] = 0.99f * U[k*256 + t] + 0.01f * cent;
}

extern "C" void kernel_launch(void* const* d_in, const int* in_sizes, int n_in,
                              void* d_out, int out_size, void* d_ws, size_t ws_size,
                              hipStream_t stream)
{
  const float* z   = (const float*)d_in[0];
  const float* g   = (const float*)d_in[1];
  const float* W1  = (const float*)d_in[3];
  const float* b1  = (const float*)d_in[4];
  const float* gam = (const float*)d_in[5];
  const float* bet = (const float*)d_in[6];
  const float* W2  = (const float*)d_in[7];
  const float* b2  = (const float*)d_in[8];
  const float* U   = (const float*)d_in[9];
  float* out = (float*)d_out;
  float* ws  = (float*)d_ws;

  float* h1 = out + OFF_ZD;                         // stash h1 in z_dense region
  unsigned short* preh = (unsigned short*)(out + OFF_S);  // W1T scratch in s region
  unsigned short* prel = preh + 65536;              // (k3 overwrites s later)

  k0_prep<<<40, 256, 0, stream>>>(W1, U, preh, prel, ws+WS_UN);
  k1_gemm1<<<1024, 512, 0, stream>>>(z, preh, prel, b1, h1, ws+WS_PSUM, ws+WS_PSQ);
  k2a<<<16, 256, 0, stream>>>(ws+WS_PSUM, ws+WS_PSQ, ws+WS_TMP);
  k2b<<<1, 256, 0, stream>>>(ws+WS_TMP, gam, bet, ws+WS_SCALE, ws+WS_SHIFT);
  k3_gemm2<<<512, 256, 0, stream>>>(h1, W2, b2, ws+WS_SCALE, ws+WS_SHIFT,
                                    out+OFF_S, ws+WS_SF);
  k4_pool<<<1024, 256, 0, stream>>>(ws+WS_SF, z, ws+WS_C,
                                    out+OFF_HDENSE, out+OFF_HFLAT,
                                    out+OFF_MASK, out+OFF_ZD,
                                    out+OFF_PHAT, g, out+OFF_G);
  k4b_p<<<1024, 256, 0, stream>>>(out+OFF_HFLAT, ws+WS_UN, out+OFF_P);
  k5a<<<256, 256, 0, stream>>>(out+OFF_HDENSE, ws+WS_PART);
  k5b<<<32, 256, 0, stream>>>(ws+WS_PART, out+OFF_MASK, U, out+OFF_UNEW);
}

// Round 14
// 271.830 us; speedup vs baseline: 1.0507x; 1.0161x over previous
//
#include <hip/hip_runtime.h>
#include <math.h>

#define NN 131072
#define BBG 1024
#define MMN 128
#define DDF 256
#define KKC 32

// ---- d_out offsets (floats), concatenated in reference return order ----
#define OFF_S      0
#define OFF_HFLAT  4194304
#define OFF_HDENSE 12582912
#define OFF_P      20971520
#define OFF_PHAT   22020096
#define OFF_ZD     23068672
#define OFF_G      56623104
#define OFF_MASK   56885248
#define OFF_UNEW   56918016

// ---- ws offsets (floats) ----
#define WS_PSUM  0          // [1024][256]
#define WS_PSQ   524288     // [1024][256]
#define WS_TMP   1048576    // [16][256]
#define WS_SCALE 1052672    // [256]
#define WS_SHIFT 1052928    // [256]
#define WS_UN    1053184    // [32][256]
#define WS_SF    1061376    // [N][32]
#define WS_C     5255680    // [B][32]
#define WS_PART  5288448    // [8*32][256]

typedef __attribute__((ext_vector_type(8))) short short8;
typedef __attribute__((ext_vector_type(4))) float f32x4;

// raw barrier with lgkm-only drain: global loads/stores stay in flight (T4)
#define LGKM_BAR() do { asm volatile("s_waitcnt lgkmcnt(0)" ::: "memory"); \
  __builtin_amdgcn_s_barrier(); __builtin_amdgcn_sched_barrier(0); } while (0)

__device__ __forceinline__ unsigned short f2bf(float x) {
  unsigned u = __float_as_uint(x);
  u += 0x7fffu + ((u >> 16) & 1u);
  return (unsigned short)(u >> 16);
}
__device__ __forceinline__ float bf2f(unsigned short h) {
  return __uint_as_float(((unsigned)h) << 16);
}

// ============ K0: W1 -> blocked bf16 hi/lo  +  Un = U/||U|| ============
__global__ __launch_bounds__(256) void k0_prep(const float* __restrict__ W1,
    const float* __restrict__ U, unsigned short* __restrict__ preh,
    unsigned short* __restrict__ prel, float* __restrict__ Un)
{
  if (blockIdx.x < 32) {
    int tid = blockIdx.x * 256 + threadIdx.x;   // < 8192
    int n = tid & 255, kq = tid >> 8;           // kq in [0,32): k = kq*8 + j
    short8 hv, lv;
    #pragma unroll
    for (int j = 0; j < 8; ++j) {
      float v = W1[(kq * 8 + j) * DDF + n];
      unsigned short hb = f2bf(v);
      hv[j] = (short)hb;
      lv[j] = (short)f2bf(v - bf2f(hb));
    }
    int base = (kq >> 2) * 8192 + (kq & 3) * 2048 + n * 8;
    *(short8*)(preh + base) = hv;
    *(short8*)(prel + base) = lv;
  } else {
    int k = (blockIdx.x - 32) * 4 + (threadIdx.x >> 6);  // 32 rows
    int l = threadIdx.x & 63;
    float4 u = *(const float4*)(U + k*256 + l*4);
    float ss = u.x*u.x + u.y*u.y + u.z*u.z + u.w*u.w;
    #pragma unroll
    for (int off = 32; off >= 1; off >>= 1) ss += __shfl_xor(ss, off);
    float inv = 1.0f / fmaxf(sqrtf(ss), 1e-12f);
    *(float4*)(Un + k*256 + l*4) = make_float4(u.x*inv, u.y*inv, u.z*inv, u.w*inv);
  }
}

// ============ K1: h1 = z@W1 + b1 via 3-term bf16x2 MFMA + column stats ========
// R13 structure: BK=32, LGKM_BAR, 2-deep z prefetch, post-barrier B prefetch.
__device__ __forceinline__ void cvt_storeA(float4 za, float4 zb,
    unsigned short* AhB, unsigned short* AlB, int arow, int ac)
{
  unsigned short h0 = f2bf(za.x), h1v = f2bf(za.y), h2 = f2bf(za.z), h3 = f2bf(za.w);
  unsigned short g0 = f2bf(zb.x), g1 = f2bf(zb.y), g2 = f2bf(zb.z), g3 = f2bf(zb.w);
  uint2 hA = make_uint2((unsigned)h0 | ((unsigned)h1v << 16),
                        (unsigned)h2 | ((unsigned)h3 << 16));
  uint2 hB = make_uint2((unsigned)g0 | ((unsigned)g1 << 16),
                        (unsigned)g2 | ((unsigned)g3 << 16));
  uint2 lA = make_uint2((unsigned)f2bf(za.x - bf2f(h0)) | ((unsigned)f2bf(za.y - bf2f(h1v)) << 16),
                        (unsigned)f2bf(za.z - bf2f(h2)) | ((unsigned)f2bf(za.w - bf2f(h3)) << 16));
  uint2 lB = make_uint2((unsigned)f2bf(zb.x - bf2f(g0)) | ((unsigned)f2bf(zb.y - bf2f(g1)) << 16),
                        (unsigned)f2bf(zb.z - bf2f(g2)) | ((unsigned)f2bf(zb.w - bf2f(g3)) << 16));
  *(uint2*)(AhB + arow * 40 + ac * 4)      = hA;
  *(uint2*)(AhB + arow * 40 + 16 + ac * 4) = hB;
  *(uint2*)(AlB + arow * 40 + ac * 4)      = lA;
  *(uint2*)(AlB + arow * 40 + 16 + ac * 4) = lB;
}

__global__ __launch_bounds__(512) void k1_gemm1(
    const float* __restrict__ z, const unsigned short* __restrict__ preh,
    const unsigned short* __restrict__ prel, const float* __restrict__ b1,
    float* __restrict__ h1, float* __restrict__ psum, float* __restrict__ psq)
{
  __shared__ __attribute__((aligned(16))) unsigned short Ah[2 * 128 * 40];
  __shared__ __attribute__((aligned(16))) unsigned short Al[2 * 128 * 40];

  const int t = threadIdx.x;
  const int l = t & 63;
  const int w = t >> 6;
  const int wr = w >> 2;
  const int wc = w & 3;
  const int lg = l >> 4;
  const int l16 = l & 15;
  const int n0 = blockIdx.x * 128;

  f32x4 acc[4][4];
  #pragma unroll
  for (int i = 0; i < 4; ++i)
    #pragma unroll
    for (int j = 0; j < 4; ++j) acc[i][j] = (f32x4)0.0f;

  const int arow = t >> 2, ac = t & 3;
  const float* zrow = z + (size_t)(n0 + arow) * DDF;
  const unsigned short* bhbase = preh + lg * 2048 + wc * 512 + l16 * 8;
  const unsigned short* blbase = prel + lg * 2048 + wc * 512 + l16 * 8;

  {
    float4 za = *(const float4*)(zrow + ac * 4);
    float4 zb = *(const float4*)(zrow + 16 + ac * 4);
    cvt_storeA(za, zb, Ah, Al, arow, ac);
  }
  float4 zaN = *(const float4*)(zrow + 32 + ac * 4);
  float4 zbN = *(const float4*)(zrow + 48 + ac * 4);
  // B(0) prefetch (prologue)
  short8 bfh[4], bfl[4];
  #pragma unroll
  for (int nf = 0; nf < 4; ++nf) {
    bfh[nf] = *(const short8*)(bhbase + nf * 128);
    bfl[nf] = *(const short8*)(blbase + nf * 128);
  }

  #pragma unroll
  for (int ks = 0; ks < 8; ++ks) {
    const int cur = (ks & 1) * 5120;
    const int nxt = 5120 - cur;
    // 2-deep z prefetch
    float4 zaF, zbF;
    if (ks < 6) {
      zaF = *(const float4*)(zrow + (ks + 2) * 32 + ac * 4);
      zbF = *(const float4*)(zrow + (ks + 2) * 32 + 16 + ac * 4);
    }
    LGKM_BAR();
    // issue B(ks+1) right after the barrier: L2 latency hides under MFMA
    short8 bfhN[4], bflN[4];
    if (ks < 7) {
      #pragma unroll
      for (int nf = 0; nf < 4; ++nf) {
        bfhN[nf] = *(const short8*)(bhbase + (ks + 1) * 8192 + nf * 128);
        bflN[nf] = *(const short8*)(blbase + (ks + 1) * 8192 + nf * 128);
      }
    }
    __builtin_amdgcn_s_setprio(1);
    #pragma unroll
    for (int mf = 0; mf < 4; ++mf) {
      const int ar = wr * 64 + mf * 16 + l16;
      short8 afh = *(const short8*)(&Ah[cur + ar * 40 + lg * 8]);
      short8 afl = *(const short8*)(&Al[cur + ar * 40 + lg * 8]);
      #pragma unroll
      for (int nf = 0; nf < 4; ++nf)
        acc[mf][nf] = __builtin_amdgcn_mfma_f32_16x16x32_bf16(afh, bfh[nf], acc[mf][nf], 0, 0, 0);
      #pragma unroll
      for (int nf = 0; nf < 4; ++nf)
        acc[mf][nf] = __builtin_amdgcn_mfma_f32_16x16x32_bf16(afl, bfh[nf], acc[mf][nf], 0, 0, 0);
      #pragma unroll
      for (int nf = 0; nf < 4; ++nf)
        acc[mf][nf] = __builtin_amdgcn_mfma_f32_16x16x32_bf16(afh, bfl[nf], acc[mf][nf], 0, 0, 0);
    }
    __builtin_amdgcn_s_setprio(0);
    if (ks < 7) {
      cvt_storeA(zaN, zbN, Ah + nxt, Al + nxt, arow, ac);
      zaN = zaF; zbN = zbF;
      #pragma unroll
      for (int nf = 0; nf < 4; ++nf) { bfh[nf] = bfhN[nf]; bfl[nf] = bflN[nf]; }
    }
  }

  float s1[4] = {0, 0, 0, 0}, s2[4] = {0, 0, 0, 0};
  #pragma unroll
  for (int nf = 0; nf < 4; ++nf) {
    int c = wc * 64 + nf * 16 + l16;
    float bb = b1[c];
    #pragma unroll
    for (int mf = 0; mf < 4; ++mf) {
      int rbase = n0 + wr * 64 + mf * 16 + lg * 4;
      #pragma unroll
      for (int j = 0; j < 4; ++j) {
        float v = acc[mf][nf][j] + bb;
        s1[nf] += v; s2[nf] += v * v;
        h1[(size_t)(rbase + j) * DDF + c] = v;
      }
    }
  }
  #pragma unroll
  for (int nf = 0; nf < 4; ++nf) {
    s1[nf] += __shfl_xor(s1[nf], 16); s1[nf] += __shfl_xor(s1[nf], 32);
    s2[nf] += __shfl_xor(s2[nf], 16); s2[nf] += __shfl_xor(s2[nf], 32);
  }
  __syncthreads();
  float* red1 = (float*)Ah;
  float* red2 = (float*)Al;
  if (l < 16) {
    #pragma unroll
    for (int nf = 0; nf < 4; ++nf) {
      red1[wr * 256 + wc * 64 + nf * 16 + l] = s1[nf];
      red2[wr * 256 + wc * 64 + nf * 16 + l] = s2[nf];
    }
  }
  __syncthreads();
  if (t < 256) {
    psum[blockIdx.x * 256 + t] = red1[t] + red1[256 + t];
    psq [blockIdx.x * 256 + t] = red2[t] + red2[256 + t];
  }
}

// ============ K2a: reduce 1024 partial rows -> 16x256 ============
__global__ __launch_bounds__(256) void k2a(const float* __restrict__ psum,
                                           const float* __restrict__ psq,
                                           float* __restrict__ tmp)
{
  int g = blockIdx.x & 7;
  const float* src = (blockIdx.x < 8) ? psum : psq;
  float acc = 0.f;
  #pragma unroll 8
  for (int r = 0; r < 128; ++r) acc += src[(g * 128 + r) * 256 + threadIdx.x];
  tmp[blockIdx.x * 256 + threadIdx.x] = acc;
}

// ============ K2b: finalize BN scale/shift ============
__global__ __launch_bounds__(256) void k2b(const float* __restrict__ tmp,
    const float* __restrict__ gam, const float* __restrict__ bet,
    float* __restrict__ scale, float* __restrict__ shift)
{
  int d = threadIdx.x;
  float s1 = 0.f, s2 = 0.f;
  #pragma unroll
  for (int g = 0; g < 8; ++g) { s1 += tmp[g*256+d]; s2 += tmp[(8+g)*256+d]; }
  float mu  = s1 * (1.0f / (float)NN);
  float var = s2 * (1.0f / (float)NN) - mu*mu;
  float inv = 1.0f / sqrtf(var + 1e-5f);
  float sc = gam[d] * inv;
  scale[d] = sc;
  shift[d] = bet[d] - mu*sc;
}

// ============ K3: BN+lrelu+GEMM2+softmax+std-filter, one wave per 64 rows ====
__global__ __launch_bounds__(256) void k3_gemm2(
    const float* __restrict__ h1, const float* __restrict__ W2,
    const float* __restrict__ b2, const float* __restrict__ scale,
    const float* __restrict__ shift, float* __restrict__ s_out,
    float* __restrict__ sf_out)
{
  __shared__ float ylds[4][64*32];
  const int t = threadIdx.x;
  const int w = t >> 6, l = t & 63;
  const int b = blockIdx.x * 2 + (w >> 1);
  const int half = w & 1;
  const int rowbase = b * MMN + half * 64;
  float* my = ylds[w];
  const int lx7 = l & 7;
  const int rsub = l >> 3;

  float acc[32];
  #pragma unroll
  for (int k = 0; k < 32; ++k) acc[k] = 0.f;

  for (int ch = 0; ch < 8; ++ch) {
    const float4 sc = *(const float4*)(scale + ch*32 + lx7*4);
    const float4 sh = *(const float4*)(shift + ch*32 + lx7*4);
    #pragma unroll
    for (int i = 0; i < 8; ++i) {
      int row = rsub + i*8;
      float4 v = *(const float4*)(h1 + (size_t)(rowbase + row)*DDF + ch*32 + lx7*4);
      float y0 = fmaf(v.x, sc.x, sh.x); y0 = y0 > 0.f ? y0 : 0.01f*y0;
      float y1 = fmaf(v.y, sc.y, sh.y); y1 = y1 > 0.f ? y1 : 0.01f*y1;
      float y2 = fmaf(v.z, sc.z, sh.z); y2 = y2 > 0.f ? y2 : 0.01f*y2;
      float y3 = fmaf(v.w, sc.w, sh.w); y3 = y3 > 0.f ? y3 : 0.01f*y3;
      *(float4*)(&my[row*32 + (lx7 ^ rsub)*4]) = make_float4(y0,y1,y2,y3);
    }
    #pragma unroll
    for (int d4 = 0; d4 < 8; ++d4) {
      float4 ya = *(const float4*)(&my[l*32 + (d4 ^ lx7)*4]);
      #pragma unroll
      for (int dd = 0; dd < 4; ++dd) {
        const float* w2r = W2 + (ch*32 + d4*4 + dd)*KKC;
        float a = (dd==0?ya.x: dd==1?ya.y: dd==2?ya.z: ya.w);
        #pragma unroll
        for (int k = 0; k < 32; ++k) acc[k] = fmaf(a, w2r[k], acc[k]);
      }
    }
  }
  #pragma unroll
  for (int k = 0; k < 32; ++k) acc[k] = (acc[k] + b2[k]) * 10.0f;
  float thr;
  {
    float m = acc[0];
    #pragma unroll
    for (int k = 1; k < 32; ++k) m = fmaxf(m, acc[k]);
    float sum = 0.f;
    #pragma unroll
    for (int k = 0; k < 32; ++k) { float e = expf(acc[k]-m); acc[k] = e; sum += e; }
    float inv = 1.0f/sum;
    float ssum = 0.f;
    #pragma unroll
    for (int k = 0; k < 32; ++k) { acc[k] *= inv; ssum += acc[k]; }
    float mean = ssum * (1.0f/32.0f);
    float var = 0.f;
    #pragma unroll
    for (int k = 0; k < 32; ++k) { float d = acc[k]-mean; var += d*d; }
    thr = sqrtf(var * (1.0f/31.0f)) + 0.03125f;
  }
  #pragma unroll
  for (int q = 0; q < 8; ++q)
    *(float4*)(&my[l*32 + (q ^ lx7)*4]) =
        make_float4(acc[q*4],acc[q*4+1],acc[q*4+2],acc[q*4+3]);
  #pragma unroll
  for (int i = 0; i < 8; ++i) {
    int fid = l + i*64;
    int row = fid >> 3, q = fid & 7;
    *(float4*)(s_out + (size_t)rowbase*KKC + fid*4) =
        *(const float4*)(&my[row*32 + (q ^ (row & 7))*4]);
  }
  #pragma unroll
  for (int k = 0; k < 32; ++k) acc[k] = acc[k] > thr ? acc[k] : 0.f;
  #pragma unroll
  for (int q = 0; q < 8; ++q)
    *(float4*)(&my[l*32 + (q ^ lx7)*4]) =
        make_float4(acc[q*4],acc[q*4+1],acc[q*4+2],acc[q*4+3]);
  #pragma unroll
  for (int i = 0; i < 8; ++i) {
    int fid = l + i*64;
    int row = fid >> 3, q = fid & 7;
    *(float4*)(sf_out + (size_t)rowbase*KKC + fid*4) =
        *(const float4*)(&my[row*32 + (q ^ (row & 7))*4]);
  }
}

// ============ K4: pooling + h_dense/h_flat/mask + zd + phat + g ============
// Chunk-loop barriers are LGKM-only: zd global-stores (no reader) stay in
// flight instead of being drained by __syncthreads' vmcnt(0) 16x.
__global__ __launch_bounds__(256) void k4_pool(
    const float* __restrict__ sf, const float* __restrict__ z,
    float* __restrict__ c_out, float* __restrict__ hdense,
    float* __restrict__ hflat, float* __restrict__ mask_out,
    float* __restrict__ zd, float* __restrict__ phat,
    const float* __restrict__ g, float* __restrict__ gout)
{
  __shared__ __align__(16) float sflds[128*32];   // 16 KB
  __shared__ __align__(16) float zlds[16*256];    // 16 KB
  __shared__ float redp[8*32];
  __shared__ float cred[32];

  const int t = threadIdx.x;
  const int w = t >> 6, l = t & 63;
  const int b = blockIdx.x;

  gout[b*256 + t] = g[b*256 + t];

  #pragma unroll
  for (int i = 0; i < 4; ++i) {
    int fid = t + i*256;
    *(float4*)(&sflds[fid*4]) = *(const float4*)(sf + (size_t)b*4096 + fid*4);
  }
  __syncthreads();
  {
    int k = t & 31, mg = t >> 5;
    float p = 0.f;
    #pragma unroll
    for (int m = 0; m < 16; ++m) p += sflds[(mg*16+m)*32 + k];
    redp[mg*32 + k] = p;
  }
  __syncthreads();
  if (t < 32) {
    float c = 0.f;
    #pragma unroll
    for (int g2 = 0; g2 < 8; ++g2) c += redp[g2*32 + t];
    cred[t] = c;
    c_out[b*32 + t] = c;
  }
  __syncthreads();
  {
    float cc = cred[t >> 3];
    float pv = cc / (cc + 1e-12f);
    int k1r = t >> 3;
    float4 ph;
    ph.x = (((t*4+0) & 31) == k1r) ? pv : 0.f;
    ph.y = (((t*4+1) & 31) == k1r) ? pv : 0.f;
    ph.z = (((t*4+2) & 31) == k1r) ? pv : 0.f;
    ph.w = (((t*4+3) & 31) == k1r) ? pv : 0.f;
    *(float4*)(phat + (size_t)b*1024 + t*4) = ph;
  }

  float acc[8][4];
  #pragma unroll
  for (int kk = 0; kk < 8; ++kk)
    #pragma unroll
    for (int j = 0; j < 4; ++j) acc[kk][j] = 0.f;

  for (int ch = 0; ch < 8; ++ch) {     // 16 rows per chunk
    #pragma unroll
    for (int i = 0; i < 4; ++i) {
      int fid = t + i*256;             // < 1024 float4s
      float4 v = *(const float4*)(z + (size_t)(b*128 + ch*16)*256 + fid*4);
      *(float4*)(&zlds[fid*4]) = v;
      *(float4*)(zd + (size_t)(b*128 + ch*16)*256 + fid*4) = v;
    }
    LGKM_BAR();                        // ds_writes visible; zd stores fly on
    #pragma unroll
    for (int mm = 0; mm < 16; ++mm) {
      float4 zv = *(const float4*)(&zlds[mm*256 + l*4]);
      float4 sa = *(const float4*)(&sflds[(ch*16+mm)*32 + w*8]);
      float4 sb = *(const float4*)(&sflds[(ch*16+mm)*32 + w*8 + 4]);
      float sv[8] = {sa.x,sa.y,sa.z,sa.w,sb.x,sb.y,sb.z,sb.w};
      #pragma unroll
      for (int kk = 0; kk < 8; ++kk) {
        acc[kk][0] = fmaf(sv[kk], zv.x, acc[kk][0]);
        acc[kk][1] = fmaf(sv[kk], zv.y, acc[kk][1]);
        acc[kk][2] = fmaf(sv[kk], zv.z, acc[kk][2]);
        acc[kk][3] = fmaf(sv[kk], zv.w, acc[kk][3]);
      }
    }
    LGKM_BAR();                        // all waves' ds_reads retired
  }
  float asum[8], mkarr[8];
  #pragma unroll
  for (int kk = 0; kk < 8; ++kk) {
    float wnv = 1.0f / fmaxf(cred[w*8+kk], 1e-12f);
    acc[kk][0]*=wnv; acc[kk][1]*=wnv; acc[kk][2]*=wnv; acc[kk][3]*=wnv;
    asum[kk] = fabsf(acc[kk][0])+fabsf(acc[kk][1])+fabsf(acc[kk][2])+fabsf(acc[kk][3]);
  }
  #pragma unroll
  for (int kk = 0; kk < 8; ++kk) {
    float a = asum[kk];
    #pragma unroll
    for (int off = 1; off < 64; off <<= 1) a += __shfl_xor(a, off);
    asum[kk] = a;
  }
  #pragma unroll
  for (int kk = 0; kk < 8; ++kk) {
    int krow = b*32 + w*8 + kk;
    float mk = asum[kk] > 0.f ? 1.0f : 0.0f;
    mkarr[kk] = mk;
    float h0=acc[kk][0], h1v=acc[kk][1], h2=acc[kk][2], h3=acc[kk][3];
    *(float4*)(hdense + (size_t)krow*256 + l*4) = make_float4(h0,h1v,h2,h3);
    *(float4*)(hflat  + (size_t)krow*256 + l*4) =
        make_float4(h0*mk,h1v*mk,h2*mk,h3*mk);
  }
  if (l == 0) {
    #pragma unroll
    for (int kk = 0; kk < 8; ++kk) mask_out[b*32 + w*8 + kk] = mkarr[kk];
  }
}

// ============ K45: fused k4b (p = hn@Un^T, blocks 0..1023) + k5a (h_dense
// partial sums, blocks 1024..1279). Independent workloads, both depend only
// on k4 -> one launch instead of two; bodies verbatim -> bit-exact.
__global__ __launch_bounds__(256) void k45_fused(
    const float* __restrict__ hflat, const float* __restrict__ Un,
    float* __restrict__ p_out, const float* __restrict__ hdense,
    float* __restrict__ part)
{
  const int t = threadIdx.x;
  if (blockIdx.x < 1024) {
    __shared__ float hl[32*260];
    __shared__ float ul[32*256];
    const int b = blockIdx.x;
    #pragma unroll
    for (int i = 0; i < 8; ++i) {
      int fid = t + i*256;
      int row = fid >> 6, c4 = fid & 63;
      *(float4*)(&hl[row*260 + c4*4]) =
          *(const float4*)(hflat + (size_t)b*8192 + fid*4);
      *(float4*)(&ul[fid*4]) = *(const float4*)(Un + fid*4);
    }
    __syncthreads();
    const int k = t & 31, k2 = (t >> 5) * 4;
    float p0=0.f, p1=0.f, p2=0.f, p3=0.f, qq=0.f;
    #pragma unroll 8
    for (int d4 = 0; d4 < 64; ++d4) {
      float4 hv = *(const float4*)(&hl[k*260 + d4*4]);
      qq = fmaf(hv.x,hv.x,fmaf(hv.y,hv.y,fmaf(hv.z,hv.z,fmaf(hv.w,hv.w,qq))));
      float4 u0 = *(const float4*)(&ul[(k2+0)*256 + d4*4]);
      float4 u1 = *(const float4*)(&ul[(k2+1)*256 + d4*4]);
      float4 u2 = *(const float4*)(&ul[(k2+2)*256 + d4*4]);
      float4 u3 = *(const float4*)(&ul[(k2+3)*256 + d4*4]);
      p0 = fmaf(hv.x,u0.x,fmaf(hv.y,u0.y,fmaf(hv.z,u0.z,fmaf(hv.w,u0.w,p0))));
      p1 = fmaf(hv.x,u1.x,fmaf(hv.y,u1.y,fmaf(hv.z,u1.z,fmaf(hv.w,u1.w,p1))));
      p2 = fmaf(hv.x,u2.x,fmaf(hv.y,u2.y,fmaf(hv.z,u2.z,fmaf(hv.w,u2.w,p2))));
      p3 = fmaf(hv.x,u3.x,fmaf(hv.y,u3.y,fmaf(hv.z,u3.z,fmaf(hv.w,u3.w,p3))));
    }
    float inv = 1.0f / fmaxf(sqrtf(qq), 1e-12f);
    *(float4*)(p_out + (size_t)(b*32 + k)*32 + k2) =
        make_float4(p0*inv, p1*inv, p2*inv, p3*inv);
  } else {
    const int bid = blockIdx.x - 1024;        // 0..255
    int k = bid & 31, seg = bid >> 5;
    float s = 0.f;
    #pragma unroll 4
    for (int i = 0; i < 128; ++i) {
      int b = seg*128 + i;
      s += hdense[(size_t)(b*32 + k)*256 + t];
    }
    part[bid*256 + t] = s;
  }
}

// ============ K5b: sizes (reshape semantics!) + centroids + U_new ============
__global__ __launch_bounds__(256) void k5b(const float* __restrict__ part,
    const float* __restrict__ maskf, const float* __restrict__ U,
    float* __restrict__ Unew)
{
  __shared__ float r4[4];
  int k = blockIdx.x, t = threadIdx.x;
  float4 mv = *(const float4*)(maskf + k*1024 + t*4);
  float m4 = mv.x + mv.y + mv.z + mv.w;
  #pragma unroll
  for (int off = 1; off < 64; off <<= 1) m4 += __shfl_xor(m4, off);
  if ((t & 63) == 0) r4[t >> 6] = m4;
  __syncthreads();
  float sizes = r4[0] + r4[1] + r4[2] + r4[3];
  float csum = 0.f;
  #pragma unroll
  for (int g = 0; g < 8; ++g) csum += part[(g*32 + k)*256 + t];
  float cent = csum / (sizes + 1e-10f);
  Unew[k*256 + t] = 0.99f * U[k*256 + t] + 0.01f * cent;
}

extern "C" void kernel_launch(void* const* d_in, const int* in_sizes, int n_in,
                              void* d_out, int out_size, void* d_ws, size_t ws_size,
                              hipStream_t stream)
{
  const float* z   = (const float*)d_in[0];
  const float* g   = (const float*)d_in[1];
  const float* W1  = (const float*)d_in[3];
  const float* b1  = (const float*)d_in[4];
  const float* gam = (const float*)d_in[5];
  const float* bet = (const float*)d_in[6];
  const float* W2  = (const float*)d_in[7];
  const float* b2  = (const float*)d_in[8];
  const float* U   = (const float*)d_in[9];
  float* out = (float*)d_out;
  float* ws  = (float*)d_ws;

  float* h1 = out + OFF_ZD;                         // stash h1 in z_dense region
  unsigned short* preh = (unsigned short*)(out + OFF_S);  // W1T scratch in s region
  unsigned short* prel = preh + 65536;              // (k3 overwrites s later)

  k0_prep<<<40, 256, 0, stream>>>(W1, U, preh, prel, ws+WS_UN);
  k1_gemm1<<<1024, 512, 0, stream>>>(z, preh, prel, b1, h1, ws+WS_PSUM, ws+WS_PSQ);
  k2a<<<16, 256, 0, stream>>>(ws+WS_PSUM, ws+WS_PSQ, ws+WS_TMP);
  k2b<<<1, 256, 0, stream>>>(ws+WS_TMP, gam, bet, ws+WS_SCALE, ws+WS_SHIFT);
  k3_gemm2<<<512, 256, 0, stream>>>(h1, W2, b2, ws+WS_SCALE, ws+WS_SHIFT,
                                    out+OFF_S, ws+WS_SF);
  k4_pool<<<1024, 256, 0, stream>>>(ws+WS_SF, z, ws+WS_C,
                                    out+OFF_HDENSE, out+OFF_HFLAT,
                                    out+OFF_MASK, out+OFF_ZD,
                                    out+OFF_PHAT, g, out+OFF_G);
  k45_fused<<<1280, 256, 0, stream>>>(out+OFF_HFLAT, ws+WS_UN, out+OFF_P,
                                      out+OFF_HDENSE, ws+WS_PART);
  k5b<<<32, 256, 0, stream>>>(ws+WS_PART, out+OFF_MASK, U, out+OFF_UNEW);
}

// Round 15
// 270.970 us; speedup vs baseline: 1.0540x; 1.0032x over previous
//
#include <hip/hip_runtime.h>
#include <math.h>

#define NN 131072
#define BBG 1024
#define MMN 128
#define DDF 256
#define KKC 32

// ---- d_out offsets (floats), concatenated in reference return order ----
#define OFF_S      0
#define OFF_HFLAT  4194304
#define OFF_HDENSE 12582912
#define OFF_P      20971520
#define OFF_PHAT   22020096
#define OFF_ZD     23068672
#define OFF_G      56623104
#define OFF_MASK   56885248
#define OFF_UNEW   56918016

// ---- ws offsets (floats) ----
#define WS_PSUM  0          // [1024][256]
#define WS_PSQ   524288     // [1024][256]
#define WS_TMP   1048576    // [16][256]
#define WS_SCALE 1052672    // [256]
#define WS_SHIFT 1052928    // [256]
#define WS_UN    1053184    // [32][256]
#define WS_SF    1061376    // [N][32]
#define WS_C     5255680    // [B][32]  (also hosts k2ab counter before k4 writes it)
#define WS_PART  5288448    // [8*32][256]

typedef __attribute__((ext_vector_type(8))) short short8;
typedef __attribute__((ext_vector_type(4))) float f32x4;

// raw barrier with lgkm-only drain: global loads/stores stay in flight (T4)
#define LGKM_BAR() do { asm volatile("s_waitcnt lgkmcnt(0)" ::: "memory"); \
  __builtin_amdgcn_s_barrier(); __builtin_amdgcn_sched_barrier(0); } while (0)

__device__ __forceinline__ unsigned short f2bf(float x) {
  unsigned u = __float_as_uint(x);
  u += 0x7fffu + ((u >> 16) & 1u);
  return (unsigned short)(u >> 16);
}
__device__ __forceinline__ float bf2f(unsigned short h) {
  return __uint_as_float(((unsigned)h) << 16);
}

// ============ K0: W1 -> blocked bf16 hi/lo  +  Un = U/||U||  + cnt=0 ========
__global__ __launch_bounds__(256) void k0_prep(const float* __restrict__ W1,
    const float* __restrict__ U, unsigned short* __restrict__ preh,
    unsigned short* __restrict__ prel, float* __restrict__ Un,
    unsigned* __restrict__ cnt)
{
  if (blockIdx.x == 0 && threadIdx.x == 0) cnt[0] = 0u;  // graph-replay-safe init
  if (blockIdx.x < 32) {
    int tid = blockIdx.x * 256 + threadIdx.x;   // < 8192
    int n = tid & 255, kq = tid >> 8;           // kq in [0,32): k = kq*8 + j
    short8 hv, lv;
    #pragma unroll
    for (int j = 0; j < 8; ++j) {
      float v = W1[(kq * 8 + j) * DDF + n];
      unsigned short hb = f2bf(v);
      hv[j] = (short)hb;
      lv[j] = (short)f2bf(v - bf2f(hb));
    }
    int base = (kq >> 2) * 8192 + (kq & 3) * 2048 + n * 8;
    *(short8*)(preh + base) = hv;
    *(short8*)(prel + base) = lv;
  } else {
    int k = (blockIdx.x - 32) * 4 + (threadIdx.x >> 6);  // 32 rows
    int l = threadIdx.x & 63;
    float4 u = *(const float4*)(U + k*256 + l*4);
    float ss = u.x*u.x + u.y*u.y + u.z*u.z + u.w*u.w;
    #pragma unroll
    for (int off = 32; off >= 1; off >>= 1) ss += __shfl_xor(ss, off);
    float inv = 1.0f / fmaxf(sqrtf(ss), 1e-12f);
    *(float4*)(Un + k*256 + l*4) = make_float4(u.x*inv, u.y*inv, u.z*inv, u.w*inv);
  }
}

// ============ K1: h1 = z@W1 + b1 via 3-term bf16x2 MFMA + column stats ========
// R13 structure: BK=32, LGKM_BAR, 2-deep z prefetch, post-barrier B prefetch.
__device__ __forceinline__ void cvt_storeA(float4 za, float4 zb,
    unsigned short* AhB, unsigned short* AlB, int arow, int ac)
{
  unsigned short h0 = f2bf(za.x), h1v = f2bf(za.y), h2 = f2bf(za.z), h3 = f2bf(za.w);
  unsigned short g0 = f2bf(zb.x), g1 = f2bf(zb.y), g2 = f2bf(zb.z), g3 = f2bf(zb.w);
  uint2 hA = make_uint2((unsigned)h0 | ((unsigned)h1v << 16),
                        (unsigned)h2 | ((unsigned)h3 << 16));
  uint2 hB = make_uint2((unsigned)g0 | ((unsigned)g1 << 16),
                        (unsigned)g2 | ((unsigned)g3 << 16));
  uint2 lA = make_uint2((unsigned)f2bf(za.x - bf2f(h0)) | ((unsigned)f2bf(za.y - bf2f(h1v)) << 16),
                        (unsigned)f2bf(za.z - bf2f(h2)) | ((unsigned)f2bf(za.w - bf2f(h3)) << 16));
  uint2 lB = make_uint2((unsigned)f2bf(zb.x - bf2f(g0)) | ((unsigned)f2bf(zb.y - bf2f(g1)) << 16),
                        (unsigned)f2bf(zb.z - bf2f(g2)) | ((unsigned)f2bf(zb.w - bf2f(g3)) << 16));
  *(uint2*)(AhB + arow * 40 + ac * 4)      = hA;
  *(uint2*)(AhB + arow * 40 + 16 + ac * 4) = hB;
  *(uint2*)(AlB + arow * 40 + ac * 4)      = lA;
  *(uint2*)(AlB + arow * 40 + 16 + ac * 4) = lB;
}

__global__ __launch_bounds__(512) void k1_gemm1(
    const float* __restrict__ z, const unsigned short* __restrict__ preh,
    const unsigned short* __restrict__ prel, const float* __restrict__ b1,
    float* __restrict__ h1, float* __restrict__ psum, float* __restrict__ psq)
{
  __shared__ __attribute__((aligned(16))) unsigned short Ah[2 * 128 * 40];
  __shared__ __attribute__((aligned(16))) unsigned short Al[2 * 128 * 40];

  const int t = threadIdx.x;
  const int l = t & 63;
  const int w = t >> 6;
  const int wr = w >> 2;
  const int wc = w & 3;
  const int lg = l >> 4;
  const int l16 = l & 15;
  const int n0 = blockIdx.x * 128;

  f32x4 acc[4][4];
  #pragma unroll
  for (int i = 0; i < 4; ++i)
    #pragma unroll
    for (int j = 0; j < 4; ++j) acc[i][j] = (f32x4)0.0f;

  const int arow = t >> 2, ac = t & 3;
  const float* zrow = z + (size_t)(n0 + arow) * DDF;
  const unsigned short* bhbase = preh + lg * 2048 + wc * 512 + l16 * 8;
  const unsigned short* blbase = prel + lg * 2048 + wc * 512 + l16 * 8;

  {
    float4 za = *(const float4*)(zrow + ac * 4);
    float4 zb = *(const float4*)(zrow + 16 + ac * 4);
    cvt_storeA(za, zb, Ah, Al, arow, ac);
  }
  float4 zaN = *(const float4*)(zrow + 32 + ac * 4);
  float4 zbN = *(const float4*)(zrow + 48 + ac * 4);
  // B(0) prefetch (prologue)
  short8 bfh[4], bfl[4];
  #pragma unroll
  for (int nf = 0; nf < 4; ++nf) {
    bfh[nf] = *(const short8*)(bhbase + nf * 128);
    bfl[nf] = *(const short8*)(blbase + nf * 128);
  }

  #pragma unroll
  for (int ks = 0; ks < 8; ++ks) {
    const int cur = (ks & 1) * 5120;
    const int nxt = 5120 - cur;
    // 2-deep z prefetch
    float4 zaF, zbF;
    if (ks < 6) {
      zaF = *(const float4*)(zrow + (ks + 2) * 32 + ac * 4);
      zbF = *(const float4*)(zrow + (ks + 2) * 32 + 16 + ac * 4);
    }
    LGKM_BAR();
    // issue B(ks+1) right after the barrier: L2 latency hides under MFMA
    short8 bfhN[4], bflN[4];
    if (ks < 7) {
      #pragma unroll
      for (int nf = 0; nf < 4; ++nf) {
        bfhN[nf] = *(const short8*)(bhbase + (ks + 1) * 8192 + nf * 128);
        bflN[nf] = *(const short8*)(blbase + (ks + 1) * 8192 + nf * 128);
      }
    }
    __builtin_amdgcn_s_setprio(1);
    #pragma unroll
    for (int mf = 0; mf < 4; ++mf) {
      const int ar = wr * 64 + mf * 16 + l16;
      short8 afh = *(const short8*)(&Ah[cur + ar * 40 + lg * 8]);
      short8 afl = *(const short8*)(&Al[cur + ar * 40 + lg * 8]);
      #pragma unroll
      for (int nf = 0; nf < 4; ++nf)
        acc[mf][nf] = __builtin_amdgcn_mfma_f32_16x16x32_bf16(afh, bfh[nf], acc[mf][nf], 0, 0, 0);
      #pragma unroll
      for (int nf = 0; nf < 4; ++nf)
        acc[mf][nf] = __builtin_amdgcn_mfma_f32_16x16x32_bf16(afl, bfh[nf], acc[mf][nf], 0, 0, 0);
      #pragma unroll
      for (int nf = 0; nf < 4; ++nf)
        acc[mf][nf] = __builtin_amdgcn_mfma_f32_16x16x32_bf16(afh, bfl[nf], acc[mf][nf], 0, 0, 0);
    }
    __builtin_amdgcn_s_setprio(0);
    if (ks < 7) {
      cvt_storeA(zaN, zbN, Ah + nxt, Al + nxt, arow, ac);
      zaN = zaF; zbN = zbF;
      #pragma unroll
      for (int nf = 0; nf < 4; ++nf) { bfh[nf] = bfhN[nf]; bfl[nf] = bflN[nf]; }
    }
  }

  float s1[4] = {0, 0, 0, 0}, s2[4] = {0, 0, 0, 0};
  #pragma unroll
  for (int nf = 0; nf < 4; ++nf) {
    int c = wc * 64 + nf * 16 + l16;
    float bb = b1[c];
    #pragma unroll
    for (int mf = 0; mf < 4; ++mf) {
      int rbase = n0 + wr * 64 + mf * 16 + lg * 4;
      #pragma unroll
      for (int j = 0; j < 4; ++j) {
        float v = acc[mf][nf][j] + bb;
        s1[nf] += v; s2[nf] += v * v;
        h1[(size_t)(rbase + j) * DDF + c] = v;
      }
    }
  }
  #pragma unroll
  for (int nf = 0; nf < 4; ++nf) {
    s1[nf] += __shfl_xor(s1[nf], 16); s1[nf] += __shfl_xor(s1[nf], 32);
    s2[nf] += __shfl_xor(s2[nf], 16); s2[nf] += __shfl_xor(s2[nf], 32);
  }
  __syncthreads();
  float* red1 = (float*)Ah;
  float* red2 = (float*)Al;
  if (l < 16) {
    #pragma unroll
    for (int nf = 0; nf < 4; ++nf) {
      red1[wr * 256 + wc * 64 + nf * 16 + l] = s1[nf];
      red2[wr * 256 + wc * 64 + nf * 16 + l] = s2[nf];
    }
  }
  __syncthreads();
  if (t < 256) {
    psum[blockIdx.x * 256 + t] = red1[t] + red1[256 + t];
    psq [blockIdx.x * 256 + t] = red2[t] + red2[256 + t];
  }
}

// ============ K2ab: partial reduce (16 blocks) + last-block BN finalize ======
// Canonical threadFenceReduction pattern: each block writes its tmp row,
// fences, atomically increments cnt; the 16th block acquires and finalizes.
// Final reduce reads the same tmp rows in the same order as the old k2b
// regardless of which block runs it -> bit-exact. No spinning -> no deadlock.
__global__ __launch_bounds__(256) void k2ab(const float* __restrict__ psum,
    const float* __restrict__ psq, float* __restrict__ tmp,
    const float* __restrict__ gam, const float* __restrict__ bet,
    float* __restrict__ scale, float* __restrict__ shift,
    unsigned* __restrict__ cnt)
{
  __shared__ unsigned done;
  int g = blockIdx.x & 7;
  const float* src = (blockIdx.x < 8) ? psum : psq;
  float acc = 0.f;
  #pragma unroll 8
  for (int r = 0; r < 128; ++r) acc += src[(g * 128 + r) * 256 + threadIdx.x];
  tmp[blockIdx.x * 256 + threadIdx.x] = acc;

  __threadfence();                      // release this thread's tmp row
  __syncthreads();                      // all threads of block have fenced
  if (threadIdx.x == 0) done = atomicAdd(cnt, 1u);
  __syncthreads();
  if (done == 15u) {                    // last block finalizes
    __threadfence();                    // acquire all blocks' tmp rows
    int d = threadIdx.x;
    float s1 = 0.f, s2 = 0.f;
    #pragma unroll
    for (int gg = 0; gg < 8; ++gg) {
      s1 += tmp[gg*256 + d];
      s2 += tmp[(8+gg)*256 + d];
    }
    float mu  = s1 * (1.0f / (float)NN);
    float var = s2 * (1.0f / (float)NN) - mu*mu;
    float inv = 1.0f / sqrtf(var + 1e-5f);
    float sc = gam[d] * inv;
    scale[d] = sc;
    shift[d] = bet[d] - mu*sc;
  }
}

// ============ K3: BN+lrelu+GEMM2+softmax+std-filter, one wave per 64 rows ====
__global__ __launch_bounds__(256) void k3_gemm2(
    const float* __restrict__ h1, const float* __restrict__ W2,
    const float* __restrict__ b2, const float* __restrict__ scale,
    const float* __restrict__ shift, float* __restrict__ s_out,
    float* __restrict__ sf_out)
{
  __shared__ float ylds[4][64*32];
  const int t = threadIdx.x;
  const int w = t >> 6, l = t & 63;
  const int b = blockIdx.x * 2 + (w >> 1);
  const int half = w & 1;
  const int rowbase = b * MMN + half * 64;
  float* my = ylds[w];
  const int lx7 = l & 7;
  const int rsub = l >> 3;

  float acc[32];
  #pragma unroll
  for (int k = 0; k < 32; ++k) acc[k] = 0.f;

  for (int ch = 0; ch < 8; ++ch) {
    const float4 sc = *(const float4*)(scale + ch*32 + lx7*4);
    const float4 sh = *(const float4*)(shift + ch*32 + lx7*4);
    #pragma unroll
    for (int i = 0; i < 8; ++i) {
      int row = rsub + i*8;
      float4 v = *(const float4*)(h1 + (size_t)(rowbase + row)*DDF + ch*32 + lx7*4);
      float y0 = fmaf(v.x, sc.x, sh.x); y0 = y0 > 0.f ? y0 : 0.01f*y0;
      float y1 = fmaf(v.y, sc.y, sh.y); y1 = y1 > 0.f ? y1 : 0.01f*y1;
      float y2 = fmaf(v.z, sc.z, sh.z); y2 = y2 > 0.f ? y2 : 0.01f*y2;
      float y3 = fmaf(v.w, sc.w, sh.w); y3 = y3 > 0.f ? y3 : 0.01f*y3;
      *(float4*)(&my[row*32 + (lx7 ^ rsub)*4]) = make_float4(y0,y1,y2,y3);
    }
    #pragma unroll
    for (int d4 = 0; d4 < 8; ++d4) {
      float4 ya = *(const float4*)(&my[l*32 + (d4 ^ lx7)*4]);
      #pragma unroll
      for (int dd = 0; dd < 4; ++dd) {
        const float* w2r = W2 + (ch*32 + d4*4 + dd)*KKC;
        float a = (dd==0?ya.x: dd==1?ya.y: dd==2?ya.z: ya.w);
        #pragma unroll
        for (int k = 0; k < 32; ++k) acc[k] = fmaf(a, w2r[k], acc[k]);
      }
    }
  }
  #pragma unroll
  for (int k = 0; k < 32; ++k) acc[k] = (acc[k] + b2[k]) * 10.0f;
  float thr;
  {
    float m = acc[0];
    #pragma unroll
    for (int k = 1; k < 32; ++k) m = fmaxf(m, acc[k]);
    float sum = 0.f;
    #pragma unroll
    for (int k = 0; k < 32; ++k) { float e = expf(acc[k]-m); acc[k] = e; sum += e; }
    float inv = 1.0f/sum;
    float ssum = 0.f;
    #pragma unroll
    for (int k = 0; k < 32; ++k) { acc[k] *= inv; ssum += acc[k]; }
    float mean = ssum * (1.0f/32.0f);
    float var = 0.f;
    #pragma unroll
    for (int k = 0; k < 32; ++k) { float d = acc[k]-mean; var += d*d; }
    thr = sqrtf(var * (1.0f/31.0f)) + 0.03125f;
  }
  #pragma unroll
  for (int q = 0; q < 8; ++q)
    *(float4*)(&my[l*32 + (q ^ lx7)*4]) =
        make_float4(acc[q*4],acc[q*4+1],acc[q*4+2],acc[q*4+3]);
  #pragma unroll
  for (int i = 0; i < 8; ++i) {
    int fid = l + i*64;
    int row = fid >> 3, q = fid & 7;
    *(float4*)(s_out + (size_t)rowbase*KKC + fid*4) =
        *(const float4*)(&my[row*32 + (q ^ (row & 7))*4]);
  }
  #pragma unroll
  for (int k = 0; k < 32; ++k) acc[k] = acc[k] > thr ? acc[k] : 0.f;
  #pragma unroll
  for (int q = 0; q < 8; ++q)
    *(float4*)(&my[l*32 + (q ^ lx7)*4]) =
        make_float4(acc[q*4],acc[q*4+1],acc[q*4+2],acc[q*4+3]);
  #pragma unroll
  for (int i = 0; i < 8; ++i) {
    int fid = l + i*64;
    int row = fid >> 3, q = fid & 7;
    *(float4*)(sf_out + (size_t)rowbase*KKC + fid*4) =
        *(const float4*)(&my[row*32 + (q ^ (row & 7))*4]);
  }
}

// ============ K4: pooling + h_dense/h_flat/mask + zd + phat + g ============
// Chunk-loop barriers are LGKM-only: zd global-stores (no reader) stay in
// flight instead of being drained by __syncthreads' vmcnt(0) 16x.
__global__ __launch_bounds__(256) void k4_pool(
    const float* __restrict__ sf, const float* __restrict__ z,
    float* __restrict__ c_out, float* __restrict__ hdense,
    float* __restrict__ hflat, float* __restrict__ mask_out,
    float* __restrict__ zd, float* __restrict__ phat,
    const float* __restrict__ g, float* __restrict__ gout)
{
  __shared__ __align__(16) float sflds[128*32];   // 16 KB
  __shared__ __align__(16) float zlds[16*256];    // 16 KB
  __shared__ float redp[8*32];
  __shared__ float cred[32];

  const int t = threadIdx.x;
  const int w = t >> 6, l = t & 63;
  const int b = blockIdx.x;

  gout[b*256 + t] = g[b*256 + t];

  #pragma unroll
  for (int i = 0; i < 4; ++i) {
    int fid = t + i*256;
    *(float4*)(&sflds[fid*4]) = *(const float4*)(sf + (size_t)b*4096 + fid*4);
  }
  __syncthreads();
  {
    int k = t & 31, mg = t >> 5;
    float p = 0.f;
    #pragma unroll
    for (int m = 0; m < 16; ++m) p += sflds[(mg*16+m)*32 + k];
    redp[mg*32 + k] = p;
  }
  __syncthreads();
  if (t < 32) {
    float c = 0.f;
    #pragma unroll
    for (int g2 = 0; g2 < 8; ++g2) c += redp[g2*32 + t];
    cred[t] = c;
    c_out[b*32 + t] = c;
  }
  __syncthreads();
  {
    float cc = cred[t >> 3];
    float pv = cc / (cc + 1e-12f);
    int k1r = t >> 3;
    float4 ph;
    ph.x = (((t*4+0) & 31) == k1r) ? pv : 0.f;
    ph.y = (((t*4+1) & 31) == k1r) ? pv : 0.f;
    ph.z = (((t*4+2) & 31) == k1r) ? pv : 0.f;
    ph.w = (((t*4+3) & 31) == k1r) ? pv : 0.f;
    *(float4*)(phat + (size_t)b*1024 + t*4) = ph;
  }

  float acc[8][4];
  #pragma unroll
  for (int kk = 0; kk < 8; ++kk)
    #pragma unroll
    for (int j = 0; j < 4; ++j) acc[kk][j] = 0.f;

  for (int ch = 0; ch < 8; ++ch) {     // 16 rows per chunk
    #pragma unroll
    for (int i = 0; i < 4; ++i) {
      int fid = t + i*256;             // < 1024 float4s
      float4 v = *(const float4*)(z + (size_t)(b*128 + ch*16)*256 + fid*4);
      *(float4*)(&zlds[fid*4]) = v;
      *(float4*)(zd + (size_t)(b*128 + ch*16)*256 + fid*4) = v;
    }
    LGKM_BAR();                        // ds_writes visible; zd stores fly on
    #pragma unroll
    for (int mm = 0; mm < 16; ++mm) {
      float4 zv = *(const float4*)(&zlds[mm*256 + l*4]);
      float4 sa = *(const float4*)(&sflds[(ch*16+mm)*32 + w*8]);
      float4 sb = *(const float4*)(&sflds[(ch*16+mm)*32 + w*8 + 4]);
      float sv[8] = {sa.x,sa.y,sa.z,sa.w,sb.x,sb.y,sb.z,sb.w};
      #pragma unroll
      for (int kk = 0; kk < 8; ++kk) {
        acc[kk][0] = fmaf(sv[kk], zv.x, acc[kk][0]);
        acc[kk][1] = fmaf(sv[kk], zv.y, acc[kk][1]);
        acc[kk][2] = fmaf(sv[kk], zv.z, acc[kk][2]);
        acc[kk][3] = fmaf(sv[kk], zv.w, acc[kk][3]);
      }
    }
    LGKM_BAR();                        // all waves' ds_reads retired
  }
  float asum[8], mkarr[8];
  #pragma unroll
  for (int kk = 0; kk < 8; ++kk) {
    float wnv = 1.0f / fmaxf(cred[w*8+kk], 1e-12f);
    acc[kk][0]*=wnv; acc[kk][1]*=wnv; acc[kk][2]*=wnv; acc[kk][3]*=wnv;
    asum[kk] = fabsf(acc[kk][0])+fabsf(acc[kk][1])+fabsf(acc[kk][2])+fabsf(acc[kk][3]);
  }
  #pragma unroll
  for (int kk = 0; kk < 8; ++kk) {
    float a = asum[kk];
    #pragma unroll
    for (int off = 1; off < 64; off <<= 1) a += __shfl_xor(a, off);
    asum[kk] = a;
  }
  #pragma unroll
  for (int kk = 0; kk < 8; ++kk) {
    int krow = b*32 + w*8 + kk;
    float mk = asum[kk] > 0.f ? 1.0f : 0.0f;
    mkarr[kk] = mk;
    float h0=acc[kk][0], h1v=acc[kk][1], h2=acc[kk][2], h3=acc[kk][3];
    *(float4*)(hdense + (size_t)krow*256 + l*4) = make_float4(h0,h1v,h2,h3);
    *(float4*)(hflat  + (size_t)krow*256 + l*4) =
        make_float4(h0*mk,h1v*mk,h2*mk,h3*mk);
  }
  if (l == 0) {
    #pragma unroll
    for (int kk = 0; kk < 8; ++kk) mask_out[b*32 + w*8 + kk] = mkarr[kk];
  }
}

// ============ K45: fused k4b (p = hn@Un^T, blocks 0..1023) + k5a (h_dense
// partial sums, blocks 1024..1279). Independent workloads, both depend only
// on k4 -> one launch instead of two; bodies verbatim -> bit-exact.
__global__ __launch_bounds__(256) void k45_fused(
    const float* __restrict__ hflat, const float* __restrict__ Un,
    float* __restrict__ p_out, const float* __restrict__ hdense,
    float* __restrict__ part)
{
  const int t = threadIdx.x;
  if (blockIdx.x < 1024) {
    __shared__ float hl[32*260];
    __shared__ float ul[32*256];
    const int b = blockIdx.x;
    #pragma unroll
    for (int i = 0; i < 8; ++i) {
      int fid = t + i*256;
      int row = fid >> 6, c4 = fid & 63;
      *(float4*)(&hl[row*260 + c4*4]) =
          *(const float4*)(hflat + (size_t)b*8192 + fid*4);
      *(float4*)(&ul[fid*4]) = *(const float4*)(Un + fid*4);
    }
    __syncthreads();
    const int k = t & 31, k2 = (t >> 5) * 4;
    float p0=0.f, p1=0.f, p2=0.f, p3=0.f, qq=0.f;
    #pragma unroll 8
    for (int d4 = 0; d4 < 64; ++d4) {
      float4 hv = *(const float4*)(&hl[k*260 + d4*4]);
      qq = fmaf(hv.x,hv.x,fmaf(hv.y,hv.y,fmaf(hv.z,hv.z,fmaf(hv.w,hv.w,qq))));
      float4 u0 = *(const float4*)(&ul[(k2+0)*256 + d4*4]);
      float4 u1 = *(const float4*)(&ul[(k2+1)*256 + d4*4]);
      float4 u2 = *(const float4*)(&ul[(k2+2)*256 + d4*4]);
      float4 u3 = *(const float4*)(&ul[(k2+3)*256 + d4*4]);
      p0 = fmaf(hv.x,u0.x,fmaf(hv.y,u0.y,fmaf(hv.z,u0.z,fmaf(hv.w,u0.w,p0))));
      p1 = fmaf(hv.x,u1.x,fmaf(hv.y,u1.y,fmaf(hv.z,u1.z,fmaf(hv.w,u1.w,p1))));
      p2 = fmaf(hv.x,u2.x,fmaf(hv.y,u2.y,fmaf(hv.z,u2.z,fmaf(hv.w,u2.w,p2))));
      p3 = fmaf(hv.x,u3.x,fmaf(hv.y,u3.y,fmaf(hv.z,u3.z,fmaf(hv.w,u3.w,p3))));
    }
    float inv = 1.0f / fmaxf(sqrtf(qq), 1e-12f);
    *(float4*)(p_out + (size_t)(b*32 + k)*32 + k2) =
        make_float4(p0*inv, p1*inv, p2*inv, p3*inv);
  } else {
    const int bid = blockIdx.x - 1024;        // 0..255
    int k = bid & 31, seg = bid >> 5;
    float s = 0.f;
    #pragma unroll 4
    for (int i = 0; i < 128; ++i) {
      int b = seg*128 + i;
      s += hdense[(size_t)(b*32 + k)*256 + t];
    }
    part[bid*256 + t] = s;
  }
}

// ============ K5b: sizes (reshape semantics!) + centroids + U_new ============
__global__ __launch_bounds__(256) void k5b(const float* __restrict__ part,
    const float* __restrict__ maskf, const float* __restrict__ U,
    float* __restrict__ Unew)
{
  __shared__ float r4[4];
  int k = blockIdx.x, t = threadIdx.x;
  float4 mv = *(const float4*)(maskf + k*1024 + t*4);
  float m4 = mv.x + mv.y + mv.z + mv.w;
  #pragma unroll
  for (int off = 1; off < 64; off <<= 1) m4 += __shfl_xor(m4, off);
  if ((t & 63) == 0) r4[t >> 6] = m4;
  __syncthreads();
  float sizes = r4[0] + r4[1] + r4[2] + r4[3];
  float csum = 0.f;
  #pragma unroll
  for (int g = 0; g < 8; ++g) csum += part[(g*32 + k)*256 + t];
  float cent = csum / (sizes + 1e-10f);
  Unew[k*256 + t] = 0.99f * U[k*256 + t] + 0.01f * cent;
}

extern "C" void kernel_launch(void* const* d_in, const int* in_sizes, int n_in,
                              void* d_out, int out_size, void* d_ws, size_t ws_size,
                              hipStream_t stream)
{
  const float* z   = (const float*)d_in[0];
  const float* g   = (const float*)d_in[1];
  const float* W1  = (const float*)d_in[3];
  const float* b1  = (const float*)d_in[4];
  const float* gam = (const float*)d_in[5];
  const float* bet = (const float*)d_in[6];
  const float* W2  = (const float*)d_in[7];
  const float* b2  = (const float*)d_in[8];
  const float* U   = (const float*)d_in[9];
  float* out = (float*)d_out;
  float* ws  = (float*)d_ws;

  float* h1 = out + OFF_ZD;                         // stash h1 in z_dense region
  unsigned short* preh = (unsigned short*)(out + OFF_S);  // W1T scratch in s region
  unsigned short* prel = preh + 65536;              // (k3 overwrites s later)
  unsigned* cnt = (unsigned*)(ws + WS_C);           // dead until k4 writes c_out

  k0_prep<<<40, 256, 0, stream>>>(W1, U, preh, prel, ws+WS_UN, cnt);
  k1_gemm1<<<1024, 512, 0, stream>>>(z, preh, prel, b1, h1, ws+WS_PSUM, ws+WS_PSQ);
  k2ab<<<16, 256, 0, stream>>>(ws+WS_PSUM, ws+WS_PSQ, ws+WS_TMP,
                               gam, bet, ws+WS_SCALE, ws+WS_SHIFT, cnt);
  k3_gemm2<<<512, 256, 0, stream>>>(h1, W2, b2, ws+WS_SCALE, ws+WS_SHIFT,
                                    out+OFF_S, ws+WS_SF);
  k4_pool<<<1024, 256, 0, stream>>>(ws+WS_SF, z, ws+WS_C,
                                    out+OFF_HDENSE, out+OFF_HFLAT,
                                    out+OFF_MASK, out+OFF_ZD,
                                    out+OFF_PHAT, g, out+OFF_G);
  k45_fused<<<1280, 256, 0, stream>>>(out+OFF_HFLAT, ws+WS_UN, out+OFF_P,
                                      out+OFF_HDENSE, ws+WS_PART);
  k5b<<<32, 256, 0, stream>>>(ws+WS_PART, out+OFF_MASK, U, out+OFF_UNEW);
}

// Round 16
// 266.003 us; speedup vs baseline: 1.0737x; 1.0187x over previous
//
#include <hip/hip_runtime.h>
#include <math.h>

#define NN 131072
#define BBG 1024
#define MMN 128
#define DDF 256
#define KKC 32

// ---- d_out offsets (floats), concatenated in reference return order ----
#define OFF_S      0
#define OFF_HFLAT  4194304
#define OFF_HDENSE 12582912
#define OFF_P      20971520
#define OFF_PHAT   22020096
#define OFF_ZD     23068672
#define OFF_G      56623104
#define OFF_MASK   56885248
#define OFF_UNEW   56918016

// ---- ws offsets (floats) ----
#define WS_PSUM  0          // [1024][256]
#define WS_PSQ   524288     // [1024][256]
#define WS_TMP   1048576    // [16][256]
#define WS_SCALE 1052672    // [256]
#define WS_SHIFT 1052928    // [256]
#define WS_UN    1053184    // [32][256]
#define WS_THR   1061376    // [N] per-row filter thresholds (was sf, now 0.5MB)
#define WS_C     5255680    // [B][32]  (also hosts k2ab counter before k4 writes it)
#define WS_PART  5288448    // [8*32][256]

typedef __attribute__((ext_vector_type(8))) short short8;
typedef __attribute__((ext_vector_type(4))) float f32x4;

// raw barrier with lgkm-only drain: global loads/stores stay in flight (T4)
#define LGKM_BAR() do { asm volatile("s_waitcnt lgkmcnt(0)" ::: "memory"); \
  __builtin_amdgcn_s_barrier(); __builtin_amdgcn_sched_barrier(0); } while (0)

__device__ __forceinline__ unsigned short f2bf(float x) {
  unsigned u = __float_as_uint(x);
  u += 0x7fffu + ((u >> 16) & 1u);
  return (unsigned short)(u >> 16);
}
__device__ __forceinline__ float bf2f(unsigned short h) {
  return __uint_as_float(((unsigned)h) << 16);
}

// ============ K0: W1 -> blocked bf16 hi/lo  +  Un = U/||U||  + cnt=0 ========
__global__ __launch_bounds__(256) void k0_prep(const float* __restrict__ W1,
    const float* __restrict__ U, unsigned short* __restrict__ preh,
    unsigned short* __restrict__ prel, float* __restrict__ Un,
    unsigned* __restrict__ cnt)
{
  if (blockIdx.x == 0 && threadIdx.x == 0) cnt[0] = 0u;  // graph-replay-safe init
  if (blockIdx.x < 32) {
    int tid = blockIdx.x * 256 + threadIdx.x;   // < 8192
    int n = tid & 255, kq = tid >> 8;           // kq in [0,32): k = kq*8 + j
    short8 hv, lv;
    #pragma unroll
    for (int j = 0; j < 8; ++j) {
      float v = W1[(kq * 8 + j) * DDF + n];
      unsigned short hb = f2bf(v);
      hv[j] = (short)hb;
      lv[j] = (short)f2bf(v - bf2f(hb));
    }
    int base = (kq >> 2) * 8192 + (kq & 3) * 2048 + n * 8;
    *(short8*)(preh + base) = hv;
    *(short8*)(prel + base) = lv;
  } else {
    int k = (blockIdx.x - 32) * 4 + (threadIdx.x >> 6);  // 32 rows
    int l = threadIdx.x & 63;
    float4 u = *(const float4*)(U + k*256 + l*4);
    float ss = u.x*u.x + u.y*u.y + u.z*u.z + u.w*u.w;
    #pragma unroll
    for (int off = 32; off >= 1; off >>= 1) ss += __shfl_xor(ss, off);
    float inv = 1.0f / fmaxf(sqrtf(ss), 1e-12f);
    *(float4*)(Un + k*256 + l*4) = make_float4(u.x*inv, u.y*inv, u.z*inv, u.w*inv);
  }
}

// ============ K1: h1 = z@W1 + b1 via 3-term bf16x2 MFMA + column stats ========
// R13 structure: BK=32, LGKM_BAR, 2-deep z prefetch, post-barrier B prefetch.
__device__ __forceinline__ void cvt_storeA(float4 za, float4 zb,
    unsigned short* AhB, unsigned short* AlB, int arow, int ac)
{
  unsigned short h0 = f2bf(za.x), h1v = f2bf(za.y), h2 = f2bf(za.z), h3 = f2bf(za.w);
  unsigned short g0 = f2bf(zb.x), g1 = f2bf(zb.y), g2 = f2bf(zb.z), g3 = f2bf(zb.w);
  uint2 hA = make_uint2((unsigned)h0 | ((unsigned)h1v << 16),
                        (unsigned)h2 | ((unsigned)h3 << 16));
  uint2 hB = make_uint2((unsigned)g0 | ((unsigned)g1 << 16),
                        (unsigned)g2 | ((unsigned)g3 << 16));
  uint2 lA = make_uint2((unsigned)f2bf(za.x - bf2f(h0)) | ((unsigned)f2bf(za.y - bf2f(h1v)) << 16),
                        (unsigned)f2bf(za.z - bf2f(h2)) | ((unsigned)f2bf(za.w - bf2f(h3)) << 16));
  uint2 lB = make_uint2((unsigned)f2bf(zb.x - bf2f(g0)) | ((unsigned)f2bf(zb.y - bf2f(g1)) << 16),
                        (unsigned)f2bf(zb.z - bf2f(g2)) | ((unsigned)f2bf(zb.w - bf2f(g3)) << 16));
  *(uint2*)(AhB + arow * 40 + ac * 4)      = hA;
  *(uint2*)(AhB + arow * 40 + 16 + ac * 4) = hB;
  *(uint2*)(AlB + arow * 40 + ac * 4)      = lA;
  *(uint2*)(AlB + arow * 40 + 16 + ac * 4) = lB;
}

__global__ __launch_bounds__(512) void k1_gemm1(
    const float* __restrict__ z, const unsigned short* __restrict__ preh,
    const unsigned short* __restrict__ prel, const float* __restrict__ b1,
    float* __restrict__ h1, float* __restrict__ psum, float* __restrict__ psq)
{
  __shared__ __attribute__((aligned(16))) unsigned short Ah[2 * 128 * 40];
  __shared__ __attribute__((aligned(16))) unsigned short Al[2 * 128 * 40];

  const int t = threadIdx.x;
  const int l = t & 63;
  const int w = t >> 6;
  const int wr = w >> 2;
  const int wc = w & 3;
  const int lg = l >> 4;
  const int l16 = l & 15;
  const int n0 = blockIdx.x * 128;

  f32x4 acc[4][4];
  #pragma unroll
  for (int i = 0; i < 4; ++i)
    #pragma unroll
    for (int j = 0; j < 4; ++j) acc[i][j] = (f32x4)0.0f;

  const int arow = t >> 2, ac = t & 3;
  const float* zrow = z + (size_t)(n0 + arow) * DDF;
  const unsigned short* bhbase = preh + lg * 2048 + wc * 512 + l16 * 8;
  const unsigned short* blbase = prel + lg * 2048 + wc * 512 + l16 * 8;

  {
    float4 za = *(const float4*)(zrow + ac * 4);
    float4 zb = *(const float4*)(zrow + 16 + ac * 4);
    cvt_storeA(za, zb, Ah, Al, arow, ac);
  }
  float4 zaN = *(const float4*)(zrow + 32 + ac * 4);
  float4 zbN = *(const float4*)(zrow + 48 + ac * 4);
  // B(0) prefetch (prologue)
  short8 bfh[4], bfl[4];
  #pragma unroll
  for (int nf = 0; nf < 4; ++nf) {
    bfh[nf] = *(const short8*)(bhbase + nf * 128);
    bfl[nf] = *(const short8*)(blbase + nf * 128);
  }

  #pragma unroll
  for (int ks = 0; ks < 8; ++ks) {
    const int cur = (ks & 1) * 5120;
    const int nxt = 5120 - cur;
    // 2-deep z prefetch
    float4 zaF, zbF;
    if (ks < 6) {
      zaF = *(const float4*)(zrow + (ks + 2) * 32 + ac * 4);
      zbF = *(const float4*)(zrow + (ks + 2) * 32 + 16 + ac * 4);
    }
    LGKM_BAR();
    // issue B(ks+1) right after the barrier: L2 latency hides under MFMA
    short8 bfhN[4], bflN[4];
    if (ks < 7) {
      #pragma unroll
      for (int nf = 0; nf < 4; ++nf) {
        bfhN[nf] = *(const short8*)(bhbase + (ks + 1) * 8192 + nf * 128);
        bflN[nf] = *(const short8*)(blbase + (ks + 1) * 8192 + nf * 128);
      }
    }
    __builtin_amdgcn_s_setprio(1);
    #pragma unroll
    for (int mf = 0; mf < 4; ++mf) {
      const int ar = wr * 64 + mf * 16 + l16;
      short8 afh = *(const short8*)(&Ah[cur + ar * 40 + lg * 8]);
      short8 afl = *(const short8*)(&Al[cur + ar * 40 + lg * 8]);
      #pragma unroll
      for (int nf = 0; nf < 4; ++nf)
        acc[mf][nf] = __builtin_amdgcn_mfma_f32_16x16x32_bf16(afh, bfh[nf], acc[mf][nf], 0, 0, 0);
      #pragma unroll
      for (int nf = 0; nf < 4; ++nf)
        acc[mf][nf] = __builtin_amdgcn_mfma_f32_16x16x32_bf16(afl, bfh[nf], acc[mf][nf], 0, 0, 0);
      #pragma unroll
      for (int nf = 0; nf < 4; ++nf)
        acc[mf][nf] = __builtin_amdgcn_mfma_f32_16x16x32_bf16(afh, bfl[nf], acc[mf][nf], 0, 0, 0);
    }
    __builtin_amdgcn_s_setprio(0);
    if (ks < 7) {
      cvt_storeA(zaN, zbN, Ah + nxt, Al + nxt, arow, ac);
      zaN = zaF; zbN = zbF;
      #pragma unroll
      for (int nf = 0; nf < 4; ++nf) { bfh[nf] = bfhN[nf]; bfl[nf] = bflN[nf]; }
    }
  }

  float s1[4] = {0, 0, 0, 0}, s2[4] = {0, 0, 0, 0};
  #pragma unroll
  for (int nf = 0; nf < 4; ++nf) {
    int c = wc * 64 + nf * 16 + l16;
    float bb = b1[c];
    #pragma unroll
    for (int mf = 0; mf < 4; ++mf) {
      int rbase = n0 + wr * 64 + mf * 16 + lg * 4;
      #pragma unroll
      for (int j = 0; j < 4; ++j) {
        float v = acc[mf][nf][j] + bb;
        s1[nf] += v; s2[nf] += v * v;
        h1[(size_t)(rbase + j) * DDF + c] = v;
      }
    }
  }
  #pragma unroll
  for (int nf = 0; nf < 4; ++nf) {
    s1[nf] += __shfl_xor(s1[nf], 16); s1[nf] += __shfl_xor(s1[nf], 32);
    s2[nf] += __shfl_xor(s2[nf], 16); s2[nf] += __shfl_xor(s2[nf], 32);
  }
  __syncthreads();
  float* red1 = (float*)Ah;
  float* red2 = (float*)Al;
  if (l < 16) {
    #pragma unroll
    for (int nf = 0; nf < 4; ++nf) {
      red1[wr * 256 + wc * 64 + nf * 16 + l] = s1[nf];
      red2[wr * 256 + wc * 64 + nf * 16 + l] = s2[nf];
    }
  }
  __syncthreads();
  if (t < 256) {
    psum[blockIdx.x * 256 + t] = red1[t] + red1[256 + t];
    psq [blockIdx.x * 256 + t] = red2[t] + red2[256 + t];
  }
}

// ============ K2ab: partial reduce (16 blocks) + last-block BN finalize ======
__global__ __launch_bounds__(256) void k2ab(const float* __restrict__ psum,
    const float* __restrict__ psq, float* __restrict__ tmp,
    const float* __restrict__ gam, const float* __restrict__ bet,
    float* __restrict__ scale, float* __restrict__ shift,
    unsigned* __restrict__ cnt)
{
  __shared__ unsigned done;
  int g = blockIdx.x & 7;
  const float* src = (blockIdx.x < 8) ? psum : psq;
  float acc = 0.f;
  #pragma unroll 8
  for (int r = 0; r < 128; ++r) acc += src[(g * 128 + r) * 256 + threadIdx.x];
  tmp[blockIdx.x * 256 + threadIdx.x] = acc;

  __threadfence();
  __syncthreads();
  if (threadIdx.x == 0) done = atomicAdd(cnt, 1u);
  __syncthreads();
  if (done == 15u) {
    __threadfence();
    int d = threadIdx.x;
    float s1 = 0.f, s2 = 0.f;
    #pragma unroll
    for (int gg = 0; gg < 8; ++gg) {
      s1 += tmp[gg*256 + d];
      s2 += tmp[(8+gg)*256 + d];
    }
    float mu  = s1 * (1.0f / (float)NN);
    float var = s2 * (1.0f / (float)NN) - mu*mu;
    float inv = 1.0f / sqrtf(var + 1e-5f);
    float sc = gam[d] * inv;
    scale[d] = sc;
    shift[d] = bet[d] - mu*sc;
  }
}

// ============ K3: BN+lrelu+GEMM2+softmax+std-thr, one wave per 64 rows ======
// Writes s (output) + per-row thr (0.5MB) — sf (17MB) is no longer stored;
// k4 recomputes the filter from identical f32 bits -> bit-exact.
__global__ __launch_bounds__(256) void k3_gemm2(
    const float* __restrict__ h1, const float* __restrict__ W2,
    const float* __restrict__ b2, const float* __restrict__ scale,
    const float* __restrict__ shift, float* __restrict__ s_out,
    float* __restrict__ thr_out)
{
  __shared__ float ylds[4][64*32];
  const int t = threadIdx.x;
  const int w = t >> 6, l = t & 63;
  const int b = blockIdx.x * 2 + (w >> 1);
  const int half = w & 1;
  const int rowbase = b * MMN + half * 64;
  float* my = ylds[w];
  const int lx7 = l & 7;
  const int rsub = l >> 3;

  float acc[32];
  #pragma unroll
  for (int k = 0; k < 32; ++k) acc[k] = 0.f;

  for (int ch = 0; ch < 8; ++ch) {
    const float4 sc = *(const float4*)(scale + ch*32 + lx7*4);
    const float4 sh = *(const float4*)(shift + ch*32 + lx7*4);
    #pragma unroll
    for (int i = 0; i < 8; ++i) {
      int row = rsub + i*8;
      float4 v = *(const float4*)(h1 + (size_t)(rowbase + row)*DDF + ch*32 + lx7*4);
      float y0 = fmaf(v.x, sc.x, sh.x); y0 = y0 > 0.f ? y0 : 0.01f*y0;
      float y1 = fmaf(v.y, sc.y, sh.y); y1 = y1 > 0.f ? y1 : 0.01f*y1;
      float y2 = fmaf(v.z, sc.z, sh.z); y2 = y2 > 0.f ? y2 : 0.01f*y2;
      float y3 = fmaf(v.w, sc.w, sh.w); y3 = y3 > 0.f ? y3 : 0.01f*y3;
      *(float4*)(&my[row*32 + (lx7 ^ rsub)*4]) = make_float4(y0,y1,y2,y3);
    }
    #pragma unroll
    for (int d4 = 0; d4 < 8; ++d4) {
      float4 ya = *(const float4*)(&my[l*32 + (d4 ^ lx7)*4]);
      #pragma unroll
      for (int dd = 0; dd < 4; ++dd) {
        const float* w2r = W2 + (ch*32 + d4*4 + dd)*KKC;
        float a = (dd==0?ya.x: dd==1?ya.y: dd==2?ya.z: ya.w);
        #pragma unroll
        for (int k = 0; k < 32; ++k) acc[k] = fmaf(a, w2r[k], acc[k]);
      }
    }
  }
  #pragma unroll
  for (int k = 0; k < 32; ++k) acc[k] = (acc[k] + b2[k]) * 10.0f;
  float thr;
  {
    float m = acc[0];
    #pragma unroll
    for (int k = 1; k < 32; ++k) m = fmaxf(m, acc[k]);
    float sum = 0.f;
    #pragma unroll
    for (int k = 0; k < 32; ++k) { float e = expf(acc[k]-m); acc[k] = e; sum += e; }
    float inv = 1.0f/sum;
    float ssum = 0.f;
    #pragma unroll
    for (int k = 0; k < 32; ++k) { acc[k] *= inv; ssum += acc[k]; }
    float mean = ssum * (1.0f/32.0f);
    float var = 0.f;
    #pragma unroll
    for (int k = 0; k < 32; ++k) { float d = acc[k]-mean; var += d*d; }
    thr = sqrtf(var * (1.0f/31.0f)) + 0.03125f;
  }
  // stage s (swizzled) -> coalesced write; thr one scalar per row
  #pragma unroll
  for (int q = 0; q < 8; ++q)
    *(float4*)(&my[l*32 + (q ^ lx7)*4]) =
        make_float4(acc[q*4],acc[q*4+1],acc[q*4+2],acc[q*4+3]);
  thr_out[rowbase + l] = thr;
  #pragma unroll
  for (int i = 0; i < 8; ++i) {
    int fid = l + i*64;
    int row = fid >> 3, q = fid & 7;
    *(float4*)(s_out + (size_t)rowbase*KKC + fid*4) =
        *(const float4*)(&my[row*32 + (q ^ (row & 7))*4]);
  }
}

// ============ K4: filter(s,thr) + pooling + h_dense/h_flat/mask + zd + phat + g
// sf recomputed inline from s + thr (identical f32 bits -> bit-exact).
__global__ __launch_bounds__(256) void k4_pool(
    const float* __restrict__ s_in, const float* __restrict__ thr_in,
    const float* __restrict__ z,
    float* __restrict__ c_out, float* __restrict__ hdense,
    float* __restrict__ hflat, float* __restrict__ mask_out,
    float* __restrict__ zd, float* __restrict__ phat,
    const float* __restrict__ g, float* __restrict__ gout)
{
  __shared__ __align__(16) float sflds[128*32];   // 16 KB (filtered s)
  __shared__ __align__(16) float zlds[16*256];    // 16 KB
  __shared__ float thrlds[128];
  __shared__ float redp[8*32];
  __shared__ float cred[32];

  const int t = threadIdx.x;
  const int w = t >> 6, l = t & 63;
  const int b = blockIdx.x;

  gout[b*256 + t] = g[b*256 + t];
  if (t < 128) thrlds[t] = thr_in[b*128 + t];

  float4 sv0 = *(const float4*)(s_in + (size_t)b*4096 + (t       )*4);
  float4 sv1 = *(const float4*)(s_in + (size_t)b*4096 + (t +  256)*4);
  float4 sv2 = *(const float4*)(s_in + (size_t)b*4096 + (t +  512)*4);
  float4 sv3 = *(const float4*)(s_in + (size_t)b*4096 + (t +  768)*4);
  __syncthreads();            // thrlds visible
  {
    // fid = t + i*256 covers row fid>>3 (one row per float4)
    float th0 = thrlds[(t      ) >> 3];
    float th1 = thrlds[(t + 256) >> 3];
    float th2 = thrlds[(t + 512) >> 3];
    float th3 = thrlds[(t + 768) >> 3];
    sv0.x = sv0.x > th0 ? sv0.x : 0.f; sv0.y = sv0.y > th0 ? sv0.y : 0.f;
    sv0.z = sv0.z > th0 ? sv0.z : 0.f; sv0.w = sv0.w > th0 ? sv0.w : 0.f;
    sv1.x = sv1.x > th1 ? sv1.x : 0.f; sv1.y = sv1.y > th1 ? sv1.y : 0.f;
    sv1.z = sv1.z > th1 ? sv1.z : 0.f; sv1.w = sv1.w > th1 ? sv1.w : 0.f;
    sv2.x = sv2.x > th2 ? sv2.x : 0.f; sv2.y = sv2.y > th2 ? sv2.y : 0.f;
    sv2.z = sv2.z > th2 ? sv2.z : 0.f; sv2.w = sv2.w > th2 ? sv2.w : 0.f;
    sv3.x = sv3.x > th3 ? sv3.x : 0.f; sv3.y = sv3.y > th3 ? sv3.y : 0.f;
    sv3.z = sv3.z > th3 ? sv3.z : 0.f; sv3.w = sv3.w > th3 ? sv3.w : 0.f;
    *(float4*)(&sflds[(t       )*4]) = sv0;
    *(float4*)(&sflds[(t +  256)*4]) = sv1;
    *(float4*)(&sflds[(t +  512)*4]) = sv2;
    *(float4*)(&sflds[(t +  768)*4]) = sv3;
  }
  __syncthreads();
  {
    int k = t & 31, mg = t >> 5;
    float p = 0.f;
    #pragma unroll
    for (int m = 0; m < 16; ++m) p += sflds[(mg*16+m)*32 + k];
    redp[mg*32 + k] = p;
  }
  __syncthreads();
  if (t < 32) {
    float c = 0.f;
    #pragma unroll
    for (int g2 = 0; g2 < 8; ++g2) c += redp[g2*32 + t];
    cred[t] = c;
    c_out[b*32 + t] = c;
  }
  __syncthreads();
  {
    float cc = cred[t >> 3];
    float pv = cc / (cc + 1e-12f);
    int k1r = t >> 3;
    float4 ph;
    ph.x = (((t*4+0) & 31) == k1r) ? pv : 0.f;
    ph.y = (((t*4+1) & 31) == k1r) ? pv : 0.f;
    ph.z = (((t*4+2) & 31) == k1r) ? pv : 0.f;
    ph.w = (((t*4+3) & 31) == k1r) ? pv : 0.f;
    *(float4*)(phat + (size_t)b*1024 + t*4) = ph;
  }

  float acc[8][4];
  #pragma unroll
  for (int kk = 0; kk < 8; ++kk)
    #pragma unroll
    for (int j = 0; j < 4; ++j) acc[kk][j] = 0.f;

  for (int ch = 0; ch < 8; ++ch) {     // 16 rows per chunk
    #pragma unroll
    for (int i = 0; i < 4; ++i) {
      int fid = t + i*256;             // < 1024 float4s
      float4 v = *(const float4*)(z + (size_t)(b*128 + ch*16)*256 + fid*4);
      *(float4*)(&zlds[fid*4]) = v;
      *(float4*)(zd + (size_t)(b*128 + ch*16)*256 + fid*4) = v;
    }
    LGKM_BAR();                        // ds_writes visible; zd stores fly on
    #pragma unroll
    for (int mm = 0; mm < 16; ++mm) {
      float4 zv = *(const float4*)(&zlds[mm*256 + l*4]);
      float4 sa = *(const float4*)(&sflds[(ch*16+mm)*32 + w*8]);
      float4 sb = *(const float4*)(&sflds[(ch*16+mm)*32 + w*8 + 4]);
      float sv[8] = {sa.x,sa.y,sa.z,sa.w,sb.x,sb.y,sb.z,sb.w};
      #pragma unroll
      for (int kk = 0; kk < 8; ++kk) {
        acc[kk][0] = fmaf(sv[kk], zv.x, acc[kk][0]);
        acc[kk][1] = fmaf(sv[kk], zv.y, acc[kk][1]);
        acc[kk][2] = fmaf(sv[kk], zv.z, acc[kk][2]);
        acc[kk][3] = fmaf(sv[kk], zv.w, acc[kk][3]);
      }
    }
    LGKM_BAR();                        // all waves' ds_reads retired
  }
  float asum[8], mkarr[8];
  #pragma unroll
  for (int kk = 0; kk < 8; ++kk) {
    float wnv = 1.0f / fmaxf(cred[w*8+kk], 1e-12f);
    acc[kk][0]*=wnv; acc[kk][1]*=wnv; acc[kk][2]*=wnv; acc[kk][3]*=wnv;
    asum[kk] = fabsf(acc[kk][0])+fabsf(acc[kk][1])+fabsf(acc[kk][2])+fabsf(acc[kk][3]);
  }
  #pragma unroll
  for (int kk = 0; kk < 8; ++kk) {
    float a = asum[kk];
    #pragma unroll
    for (int off = 1; off < 64; off <<= 1) a += __shfl_xor(a, off);
    asum[kk] = a;
  }
  #pragma unroll
  for (int kk = 0; kk < 8; ++kk) {
    int krow = b*32 + w*8 + kk;
    float mk = asum[kk] > 0.f ? 1.0f : 0.0f;
    mkarr[kk] = mk;
    float h0=acc[kk][0], h1v=acc[kk][1], h2=acc[kk][2], h3=acc[kk][3];
    *(float4*)(hdense + (size_t)krow*256 + l*4) = make_float4(h0,h1v,h2,h3);
    *(float4*)(hflat  + (size_t)krow*256 + l*4) =
        make_float4(h0*mk,h1v*mk,h2*mk,h3*mk);
  }
  if (l == 0) {
    #pragma unroll
    for (int kk = 0; kk < 8; ++kk) mask_out[b*32 + w*8 + kk] = mkarr[kk];
  }
}

// ============ K45: fused k4b (p = hn@Un^T, blocks 0..1023) + k5a (h_dense
// partial sums, blocks 1024..1279).
__global__ __launch_bounds__(256) void k45_fused(
    const float* __restrict__ hflat, const float* __restrict__ Un,
    float* __restrict__ p_out, const float* __restrict__ hdense,
    float* __restrict__ part)
{
  const int t = threadIdx.x;
  if (blockIdx.x < 1024) {
    __shared__ float hl[32*260];
    __shared__ float ul[32*256];
    const int b = blockIdx.x;
    #pragma unroll
    for (int i = 0; i < 8; ++i) {
      int fid = t + i*256;
      int row = fid >> 6, c4 = fid & 63;
      *(float4*)(&hl[row*260 + c4*4]) =
          *(const float4*)(hflat + (size_t)b*8192 + fid*4);
      *(float4*)(&ul[fid*4]) = *(const float4*)(Un + fid*4);
    }
    __syncthreads();
    const int k = t & 31, k2 = (t >> 5) * 4;
    float p0=0.f, p1=0.f, p2=0.f, p3=0.f, qq=0.f;
    #pragma unroll 8
    for (int d4 = 0; d4 < 64; ++d4) {
      float4 hv = *(const float4*)(&hl[k*260 + d4*4]);
      qq = fmaf(hv.x,hv.x,fmaf(hv.y,hv.y,fmaf(hv.z,hv.z,fmaf(hv.w,hv.w,qq))));
      float4 u0 = *(const float4*)(&ul[(k2+0)*256 + d4*4]);
      float4 u1 = *(const float4*)(&ul[(k2+1)*256 + d4*4]);
      float4 u2 = *(const float4*)(&ul[(k2+2)*256 + d4*4]);
      float4 u3 = *(const float4*)(&ul[(k2+3)*256 + d4*4]);
      p0 = fmaf(hv.x,u0.x,fmaf(hv.y,u0.y,fmaf(hv.z,u0.z,fmaf(hv.w,u0.w,p0))));
      p1 = fmaf(hv.x,u1.x,fmaf(hv.y,u1.y,fmaf(hv.z,u1.z,fmaf(hv.w,u1.w,p1))));
      p2 = fmaf(hv.x,u2.x,fmaf(hv.y,u2.y,fmaf(hv.z,u2.z,fmaf(hv.w,u2.w,p2))));
      p3 = fmaf(hv.x,u3.x,fmaf(hv.y,u3.y,fmaf(hv.z,u3.z,fmaf(hv.w,u3.w,p3))));
    }
    float inv = 1.0f / fmaxf(sqrtf(qq), 1e-12f);
    *(float4*)(p_out + (size_t)(b*32 + k)*32 + k2) =
        make_float4(p0*inv, p1*inv, p2*inv, p3*inv);
  } else {
    const int bid = blockIdx.x - 1024;        // 0..255
    int k = bid & 31, seg = bid >> 5;
    float s = 0.f;
    #pragma unroll 4
    for (int i = 0; i < 128; ++i) {
      int b = seg*128 + i;
      s += hdense[(size_t)(b*32 + k)*256 + t];
    }
    part[bid*256 + t] = s;
  }
}

// ============ K5b: sizes (reshape semantics!) + centroids + U_new ============
__global__ __launch_bounds__(256) void k5b(const float* __restrict__ part,
    const float* __restrict__ maskf, const float* __restrict__ U,
    float* __restrict__ Unew)
{
  __shared__ float r4[4];
  int k = blockIdx.x, t = threadIdx.x;
  float4 mv = *(const float4*)(maskf + k*1024 + t*4);
  float m4 = mv.x + mv.y + mv.z + mv.w;
  #pragma unroll
  for (int off = 1; off < 64; off <<= 1) m4 += __shfl_xor(m4, off);
  if ((t & 63) == 0) r4[t >> 6] = m4;
  __syncthreads();
  float sizes = r4[0] + r4[1] + r4[2] + r4[3];
  float csum = 0.f;
  #pragma unroll
  for (int g = 0; g < 8; ++g) csum += part[(g*32 + k)*256 + t];
  float cent = csum / (sizes + 1e-10f);
  Unew[k*256 + t] = 0.99f * U[k*256 + t] + 0.01f * cent;
}

extern "C" void kernel_launch(void* const* d_in, const int* in_sizes, int n_in,
                              void* d_out, int out_size, void* d_ws, size_t ws_size,
                              hipStream_t stream)
{
  const float* z   = (const float*)d_in[0];
  const float* g   = (const float*)d_in[1];
  const float* W1  = (const float*)d_in[3];
  const float* b1  = (const float*)d_in[4];
  const float* gam = (const float*)d_in[5];
  const float* bet = (const float*)d_in[6];
  const float* W2  = (const float*)d_in[7];
  const float* b2  = (const float*)d_in[8];
  const float* U   = (const float*)d_in[9];
  float* out = (float*)d_out;
  float* ws  = (float*)d_ws;

  float* h1 = out + OFF_ZD;                         // stash h1 in z_dense region
  unsigned short* preh = (unsigned short*)(out + OFF_S);  // W1T scratch in s region
  unsigned short* prel = preh + 65536;              // (k3 overwrites s later)
  unsigned* cnt = (unsigned*)(ws + WS_C);           // dead until k4 writes c_out

  k0_prep<<<40, 256, 0, stream>>>(W1, U, preh, prel, ws+WS_UN, cnt);
  k1_gemm1<<<1024, 512, 0, stream>>>(z, preh, prel, b1, h1, ws+WS_PSUM, ws+WS_PSQ);
  k2ab<<<16, 256, 0, stream>>>(ws+WS_PSUM, ws+WS_PSQ, ws+WS_TMP,
                               gam, bet, ws+WS_SCALE, ws+WS_SHIFT, cnt);
  k3_gemm2<<<512, 256, 0, stream>>>(h1, W2, b2, ws+WS_SCALE, ws+WS_SHIFT,
                                    out+OFF_S, ws+WS_THR);
  k4_pool<<<1024, 256, 0, stream>>>(out+OFF_S, ws+WS_THR, z, ws+WS_C,
                                    out+OFF_HDENSE, out+OFF_HFLAT,
                                    out+OFF_MASK, out+OFF_ZD,
                                    out+OFF_PHAT, g, out+OFF_G);
  k45_fused<<<1280, 256, 0, stream>>>(out+OFF_HFLAT, ws+WS_UN, out+OFF_P,
                                      out+OFF_HDENSE, ws+WS_PART);
  k5b<<<32, 256, 0, stream>>>(ws+WS_PART, out+OFF_MASK, U, out+OFF_UNEW);
}